// Round 7
// baseline (318.532 us; speedup 1.0000x reference)
//
#include <hip/hip_runtime.h>
#include <hip/hip_bf16.h>

typedef __attribute__((ext_vector_type(4))) float f32x4;
typedef __attribute__((ext_vector_type(8))) short bf16x8;
typedef __attribute__((ext_vector_type(4))) short short4v;

#define DEVI __device__ __forceinline__

constexpr int Bc = 2, Tc = 2048, Dc = 2048, Hc = 32, KVc = 8, HDc = 64;
constexpr int GRP = Hc / KVc;  // 4
constexpr float EPSc = 1e-6f;
// SCALE * log2(e) folded into Q so softmax uses exp2
constexpr float QMULT = 0.125f * 1.4426950408889634f;

DEVI short f2b(float f) {
    __hip_bfloat16 h = __float2bfloat16(f);
    short s;
    __builtin_memcpy(&s, &h, sizeof(short));
    return s;
}
DEVI float b2f(short s) {
    unsigned int u = ((unsigned int)(unsigned short)s) << 16;
    float f;
    __builtin_memcpy(&f, &u, sizeof(float));
    return f;
}

#define GLOAD16(g, l)                                                        \
    __builtin_amdgcn_global_load_lds(                                        \
        (const __attribute__((address_space(1))) void*)(g),                  \
        (__attribute__((address_space(3))) void*)(l), 16, 0, 0)

// ---------------------------------------------------------------------------
// prep: f32 -> bf16 convert (x), each thread 8 elems
// ---------------------------------------------------------------------------
__global__ __launch_bounds__(256) void convert_x(const float* __restrict__ in,
                                                 short* __restrict__ out) {
    size_t i = ((size_t)blockIdx.x * 256 + threadIdx.x) * 8;
    float4 a = *reinterpret_cast<const float4*>(in + i);
    float4 b = *reinterpret_cast<const float4*>(in + i + 4);
    bf16x8 o = {f2b(a.x), f2b(a.y), f2b(a.z), f2b(a.w),
                f2b(b.x), f2b(b.y), f2b(b.z), f2b(b.w)};
    *reinterpret_cast<bf16x8*>(out + i) = o;
}

// ---------------------------------------------------------------------------
// prep: transpose weight f32 (R x C) -> bf16 (C x R).  grid (C/64, R/64)
// ---------------------------------------------------------------------------
__global__ __launch_bounds__(256) void tr_w(const float* __restrict__ in,
                                            short* __restrict__ out, int R, int C) {
    __shared__ __align__(16) short t[64][72];
    const int n0 = blockIdx.x * 64, k0 = blockIdx.y * 64;
    const int rl = threadIdx.x >> 2, q = threadIdx.x & 3;
#pragma unroll
    for (int jj = 0; jj < 4; ++jj) {
        float4 v = *reinterpret_cast<const float4*>(in + (size_t)(k0 + rl) * C + n0 + q * 16 + jj * 4);
        short4v s = {f2b(v.x), f2b(v.y), f2b(v.z), f2b(v.w)};
        *reinterpret_cast<short4v*>(&t[rl][q * 16 + jj * 4]) = s;
    }
    __syncthreads();
    alignas(16) short buf[16];
#pragma unroll
    for (int e = 0; e < 16; ++e) buf[e] = t[q * 16 + e][rl];
    short* dst = out + (size_t)(n0 + rl) * R + k0 + q * 16;
    *reinterpret_cast<int4*>(dst) = reinterpret_cast<int4*>(buf)[0];
    *reinterpret_cast<int4*>(dst + 8) = reinterpret_cast<int4*>(buf)[1];
}

// ---------------------------------------------------------------------------
// 8-phase GEMM (m201-style): C(MxN) = A(MxK,bf16) * Bt(NxK,bf16)^T
// BM=256 x BN tile, BK=64, 512 thr (8 waves, 2M x 4N), per-wave 128 x BN/4.
// Dbuf LDS, counted vmcnt(2) once per K-tile (prefetch stays in flight across
// the 4 phases), XOR chunk-swizzle (pre-swizzled source, XOR'd read),
// setprio(1) around each 16-MFMA cluster.
// Phase p: kk = p>>1 (K-half), qi = p&1 (M-half of the wave's 128 rows).
// ---------------------------------------------------------------------------
template <int BN, typename CT>
__global__ __launch_bounds__(512, 2) void gemm8p(const short* __restrict__ A,
                                                 const short* __restrict__ Bt,
                                                 CT* __restrict__ C, int M, int N, int K) {
    constexpr int NJ = BN / 64;  // j-quadrants per wave; also B stage rounds
    __shared__ __align__(16) short sA[2][256 * 64];
    __shared__ __align__(16) short sB[2][BN * 64];

    const int tid = threadIdx.x;
    const int wave = tid >> 6, lane = tid & 63;
    const int lhi = lane >> 4, llo = lane & 15;
    const int bm = blockIdx.y * 256, bn = blockIdx.x * BN;
    const int wm = (wave >> 2) * 128, wn = (wave & 3) * (BN / 4);

    // staging addresses: element cc = l*512+tid; row = cc>>3; source chunk
    // pre-swizzled by ^(row&7); LDS dest linear at cc*8.
    const short* agp[4];
    int alds[4];
#pragma unroll
    for (int l = 0; l < 4; ++l) {
        int cc = l * 512 + tid;
        int r = cc >> 3, ck = (cc & 7) ^ (r & 7);
        agp[l] = A + (size_t)(bm + r) * K + ck * 8;
        alds[l] = cc * 8;
    }
    const short* bgp[NJ];
    int blds[NJ];
#pragma unroll
    for (int l = 0; l < NJ; ++l) {
        int cc = l * 512 + tid;
        int r = cc >> 3, ck = (cc & 7) ^ (r & 7);
        bgp[l] = Bt + (size_t)(bn + r) * K + ck * 8;
        blds[l] = cc * 8;
    }

    f32x4 acc[8][NJ] = {};

    // prologue: stage K-tile 0 into buf 0
#pragma unroll
    for (int l = 0; l < 4; ++l) GLOAD16(agp[l], &sA[0][alds[l]]);
#pragma unroll
    for (int l = 0; l < NJ; ++l) GLOAD16(bgp[l], &sB[0][blds[l]]);

    int c = 0;
    // read-side swizzled chunk offsets (lane-constant; row&7 == llo&7)
    const int co[2] = {((lhi ^ (llo & 7)) << 3), (((4 + lhi) ^ (llo & 7)) << 3)};

#pragma unroll 1
    for (int k0 = 0; k0 < K; k0 += 64) {
        const bool notlast = (k0 + 64) < K;
        bf16x8 bfr[NJ];
#pragma unroll
        for (int p = 0; p < 4; ++p) {
            // issue prefetch for next K-tile (1-2 loads per phase)
            if (notlast) {
                GLOAD16(agp[p] + k0 + 64, &sA[c ^ 1][alds[p]]);
                if (p < NJ) GLOAD16(bgp[p] + k0 + 64, &sB[c ^ 1][blds[p]]);
            }
            if (p == 0) {
                // validate current buffer: drain prev tile's loads, keep the
                // 2 just-issued in flight (counted vmcnt, never 0 mid-loop)
                if (notlast)
                    asm volatile("s_waitcnt vmcnt(2)" ::: "memory");
                else
                    asm volatile("s_waitcnt vmcnt(0)" ::: "memory");
                __builtin_amdgcn_s_barrier();
                asm volatile("" ::: "memory");
            }
            const int kk = p >> 1, qi = p & 1;
            if ((p & 1) == 0) {  // (re)load B-frags for this K-half
#pragma unroll
                for (int j = 0; j < NJ; ++j)
                    bfr[j] = *reinterpret_cast<const bf16x8*>(
                        &sB[c][(wn + j * 16 + llo) * 64 + co[kk]]);
            }
            __builtin_amdgcn_s_setprio(1);
#pragma unroll
            for (int ii = 0; ii < 4; ++ii) {
                bf16x8 af = *reinterpret_cast<const bf16x8*>(
                    &sA[c][(wm + qi * 64 + ii * 16 + llo) * 64 + co[kk]]);
#pragma unroll
                for (int j = 0; j < NJ; ++j)
                    acc[qi * 4 + ii][j] =
                        __builtin_amdgcn_mfma_f32_16x16x32_bf16(af, bfr[j], acc[qi * 4 + ii][j], 0, 0, 0);
            }
            __builtin_amdgcn_s_setprio(0);
            asm volatile("" ::: "memory");
            __builtin_amdgcn_s_barrier();
        }
        c ^= 1;
    }

    // epilogue
#pragma unroll
    for (int i = 0; i < 8; ++i)
#pragma unroll
        for (int j = 0; j < NJ; ++j)
#pragma unroll
            for (int r = 0; r < 4; ++r) {
                size_t idx = (size_t)(bm + wm + i * 16 + lhi * 4 + r) * N + bn + wn + j * 16 + llo;
                if constexpr (sizeof(CT) == 2)
                    C[idx] = f2b(acc[i][j][r]);
                else
                    C[idx] = acc[i][j][r];
            }
}

// ---------------------------------------------------------------------------
// fuse: RMSNorm + RoPE + scale, bf16 (B*T rows, stride ldin) -> bf16 (B,Hx,T,64)
// one 64-lane wave per row
// ---------------------------------------------------------------------------
__global__ __launch_bounds__(256) void fuse_qk(const short* __restrict__ in,
                                               const float* __restrict__ scale,
                                               short* __restrict__ out, int Hx, int ldin,
                                               float mult) {
    int wid = (blockIdx.x * 256 + threadIdx.x) >> 6;
    int d = threadIdx.x & 63;
    if (wid >= Bc * Tc * Hx) return;
    int h = wid % Hx;
    int bt = wid / Hx;
    int t = bt % Tc;
    int b = bt / Tc;

    float v = b2f(in[(size_t)bt * ldin + h * 64 + d]);
    float ss = v * v;
#pragma unroll
    for (int m = 1; m < 64; m <<= 1) ss += __shfl_xor(ss, m);
    v = v / sqrtf(ss * (1.0f / 64.0f) + EPSc) * scale[d];

    int i = d & 31;
    float inv_f = exp2f(-0.41524101186092029f * (float)i);  // theta^(-i/32)
    float ang = (float)t * inv_f;
    float sn, cs;
    sincosf(ang, &sn, &cs);
    float other = __shfl_xor(v, 32);
    float o = (d < 32) ? (v * cs - other * sn) : (v * cs + other * sn);
    o *= mult;
    out[((size_t)(b * Hx + h) * Tc + t) * 64 + d] = f2b(o);
}

// ---------------------------------------------------------------------------
// fuse: V rows (stride ldin, base pre-offset to V cols) -> transposed tiles
// vt[b][kv][tile][d(64)][t_local(64)].  grid (32 tiles, 8 kv, 2 b)
// ---------------------------------------------------------------------------
__global__ __launch_bounds__(256) void fuse_vt(const short* __restrict__ vsrc,
                                               short* __restrict__ vt, int ldin) {
    __shared__ __align__(16) short t[64][72];
    const int tile = blockIdx.x, kv = blockIdx.y, b = blockIdx.z;
    const int tl = threadIdx.x >> 2, q = threadIdx.x & 3;
    const short* src = vsrc + (size_t)(b * 2048 + tile * 64 + tl) * ldin + kv * 64 + q * 16;
    *reinterpret_cast<bf16x8*>(&t[tl][q * 16]) = *reinterpret_cast<const bf16x8*>(src);
    *reinterpret_cast<bf16x8*>(&t[tl][q * 16 + 8]) = *reinterpret_cast<const bf16x8*>(src + 8);
    __syncthreads();
    alignas(16) short buf[16];
#pragma unroll
    for (int e = 0; e < 16; ++e) buf[e] = t[q * 16 + e][tl];
    short* dst = vt + ((size_t)(b * 8 + kv) * 32 + tile) * 4096 + tl * 64 + q * 16;
    *reinterpret_cast<int4*>(dst) = reinterpret_cast<int4*>(buf)[0];
    *reinterpret_cast<int4*>(dst + 8) = reinterpret_cast<int4*>(buf)[1];
}

// ---------------------------------------------------------------------------
// Flash attention, causal GQA, swapped-QK^T form, double-buffered K/V,
// load-balanced: block p handles q-tiles (15-p) then p  => 34 iters/block.
// grid (8 pairs, 32 h, 2 b); 256 thr = 4 waves, 32 q rows per wave per tile.
// Online softmax with defer-max (T13): skip O-rescale while tile max stays
// within 8 (exp2 units) of the running max.
// ---------------------------------------------------------------------------
__global__ __launch_bounds__(256) void attn_fwd(const short* __restrict__ Qb,
                                                const short* __restrict__ Kb,
                                                const short* __restrict__ Vt,
                                                short* __restrict__ Ob) {
    __shared__ __align__(16) short sK[2][64 * 64];
    __shared__ __align__(16) short sV[2][64 * 64];
    __shared__ __align__(16) short sP[4][32 * 72];

    const int pair = blockIdx.x;  // 0..7
    const int h = blockIdx.y, b = blockIdx.z;
    const int kvh = h >> 2;
    const int tid = threadIdx.x, wave = tid >> 6, lane = tid & 63;
    const int lhi = lane >> 4, llo = lane & 15;

    const short* Qp = Qb + (size_t)(b * Hc + h) * Tc * 64;
    const short* Kp = Kb + (size_t)(b * KVc + kvh) * Tc * 64;
    const short* Vp = Vt + (size_t)(b * KVc + kvh) * 32 * 4096;

    // per-thread staging addresses (4 GLOAD16 per tile)
    const int srow0 = tid >> 3, sslot0 = tid & 7;
    const int srow1 = (256 + tid) >> 3, sslot1 = tid & 7;
    const int soff0 = (sslot0 ^ (srow0 & 7)) * 8;
    const int soff1 = (sslot1 ^ (srow1 & 7)) * 8;

#pragma unroll 1
    for (int sub = 0; sub < 2; ++sub) {
        const int qt = sub ? pair : 15 - pair;
        const int Q0 = qt * 128 + wave * 32;
        const int ktmax_w = (Q0 + 31) >> 6;
        const int nkt = 2 * qt + 2;

        bf16x8 qf[2][2];
#pragma unroll
        for (int q16 = 0; q16 < 2; ++q16)
#pragma unroll
            for (int kk = 0; kk < 2; ++kk)
                qf[q16][kk] = *reinterpret_cast<const bf16x8*>(
                    Qp + (size_t)(Q0 + q16 * 16 + llo) * 64 + kk * 32 + lhi * 8);

        f32x4 o[2][4] = {};
        float mreg[2] = {-1e30f, -1e30f};
        float lreg[2] = {0.f, 0.f};

        // prologue: stage tile 0 into buf 0
        {
            GLOAD16(Kp + (size_t)srow0 * 64 + soff0, &sK[0][tid * 8]);
            GLOAD16(Vp + (size_t)srow0 * 64 + soff0, &sV[0][tid * 8]);
            GLOAD16(Kp + (size_t)srow1 * 64 + soff1, &sK[0][(256 + tid) * 8]);
            GLOAD16(Vp + (size_t)srow1 * 64 + soff1, &sV[0][(256 + tid) * 8]);
        }
        int c = 0;

#pragma unroll 1
        for (int kt = 0; kt < nkt; ++kt) {
            const bool has_next = (kt + 1) < nkt;
            if (has_next) {
                const size_t kbase = (size_t)(kt + 1) * 4096;
                GLOAD16(Kp + kbase + srow0 * 64 + soff0, &sK[c ^ 1][tid * 8]);
                GLOAD16(Vp + kbase + srow0 * 64 + soff0, &sV[c ^ 1][tid * 8]);
                GLOAD16(Kp + kbase + srow1 * 64 + soff1, &sK[c ^ 1][(256 + tid) * 8]);
                GLOAD16(Vp + kbase + srow1 * 64 + soff1, &sV[c ^ 1][(256 + tid) * 8]);
                asm volatile("s_waitcnt vmcnt(4)" ::: "memory");
            } else {
                asm volatile("s_waitcnt vmcnt(0)" ::: "memory");
            }
            __builtin_amdgcn_s_barrier();
            asm volatile("" ::: "memory");  // keep ds_reads below the barrier

            if (kt <= ktmax_w) {
                const short* sKc = sK[c];
                const short* sVc = sV[c];
                // S^T = K Q^T : C[kv_local=lhi*4+r][q_local=llo] per (n, q16)
                f32x4 st[2][4];
#pragma unroll
                for (int n = 0; n < 4; ++n) {
                    int krow = n * 16 + llo;
                    bf16x8 ka0 = *reinterpret_cast<const bf16x8*>(
                        &sKc[krow * 64 + ((lhi ^ (krow & 7)) << 3)]);
                    bf16x8 ka1 = *reinterpret_cast<const bf16x8*>(
                        &sKc[krow * 64 + (((4 + lhi) ^ (krow & 7)) << 3)]);
                    f32x4 z = {0.f, 0.f, 0.f, 0.f};
                    st[0][n] = __builtin_amdgcn_mfma_f32_16x16x32_bf16(ka0, qf[0][0], z, 0, 0, 0);
                    st[0][n] = __builtin_amdgcn_mfma_f32_16x16x32_bf16(ka1, qf[0][1], st[0][n], 0, 0, 0);
                    st[1][n] = __builtin_amdgcn_mfma_f32_16x16x32_bf16(ka0, qf[1][0], z, 0, 0, 0);
                    st[1][n] = __builtin_amdgcn_mfma_f32_16x16x32_bf16(ka1, qf[1][1], st[1][n], 0, 0, 0);
                }
                if (kt == ktmax_w) {  // causal mask (diagonal region only)
#pragma unroll
                    for (int q16 = 0; q16 < 2; ++q16) {
                        int qg = Q0 + q16 * 16 + llo;
#pragma unroll
                        for (int n = 0; n < 4; ++n)
#pragma unroll
                            for (int r = 0; r < 4; ++r) {
                                int kvg = kt * 64 + n * 16 + lhi * 4 + r;
                                if (kvg > qg) st[q16][n][r] = -1e30f;
                            }
                    }
                }
                // per-row tile max (lanes sharing llo hold the same row)
                float pm[2];
#pragma unroll
                for (int q16 = 0; q16 < 2; ++q16) {
                    float p = st[q16][0][0];
#pragma unroll
                    for (int n = 0; n < 4; ++n)
#pragma unroll
                        for (int r = 0; r < 4; ++r) p = fmaxf(p, st[q16][n][r]);
                    p = fmaxf(p, __shfl_xor(p, 16));
                    p = fmaxf(p, __shfl_xor(p, 32));
                    pm[q16] = p;
                }
                // defer-max: only rescale when tile max grew past running max + 8
                bool defer = __all((pm[0] - mreg[0] <= 8.f) && (pm[1] - mreg[1] <= 8.f));
                if (!defer) {
                    float alpha[2];
#pragma unroll
                    for (int q16 = 0; q16 < 2; ++q16) {
                        float mn = fmaxf(mreg[q16], pm[q16]);
                        alpha[q16] = __builtin_amdgcn_exp2f(mreg[q16] - mn);
                        mreg[q16] = mn;
                        lreg[q16] *= alpha[q16];
                    }
#pragma unroll
                    for (int q16 = 0; q16 < 2; ++q16)
#pragma unroll
                        for (int r = 0; r < 4; ++r) {
                            float ar = __shfl(alpha[q16], lhi * 4 + r);
#pragma unroll
                            for (int j = 0; j < 4; ++j) o[q16][j][r] *= ar;
                        }
                }
                // P = exp2(S - m); row sums
#pragma unroll
                for (int q16 = 0; q16 < 2; ++q16) {
                    float ps = 0.f;
#pragma unroll
                    for (int n = 0; n < 4; ++n)
#pragma unroll
                        for (int r = 0; r < 4; ++r) {
                            float p = __builtin_amdgcn_exp2f(st[q16][n][r] - mreg[q16]);
                            st[q16][n][r] = p;
                            ps += p;
                        }
                    ps += __shfl_xor(ps, 16);
                    ps += __shfl_xor(ps, 32);
                    lreg[q16] += ps;
                }
                // store P rows to wave-private LDS (b64 stores)
#pragma unroll
                for (int q16 = 0; q16 < 2; ++q16)
#pragma unroll
                    for (int n = 0; n < 4; ++n) {
                        short4v p4 = {f2b(st[q16][n][0]), f2b(st[q16][n][1]),
                                      f2b(st[q16][n][2]), f2b(st[q16][n][3])};
                        *reinterpret_cast<short4v*>(
                            &sP[wave][(q16 * 16 + llo) * 72 + n * 16 + lhi * 4]) = p4;
                    }
                // O += P V
#pragma unroll
                for (int kk = 0; kk < 2; ++kk) {
                    bf16x8 pa0 = *reinterpret_cast<const bf16x8*>(
                        &sP[wave][(0 * 16 + llo) * 72 + kk * 32 + lhi * 8]);
                    bf16x8 pa1 = *reinterpret_cast<const bf16x8*>(
                        &sP[wave][(1 * 16 + llo) * 72 + kk * 32 + lhi * 8]);
#pragma unroll
                    for (int j = 0; j < 4; ++j) {
                        int vrow = j * 16 + llo;
                        bf16x8 vf = *reinterpret_cast<const bf16x8*>(
                            &sVc[vrow * 64 + ((((kk * 4) + lhi) ^ (vrow & 7)) << 3)]);
                        o[0][j] = __builtin_amdgcn_mfma_f32_16x16x32_bf16(pa0, vf, o[0][j], 0, 0, 0);
                        o[1][j] = __builtin_amdgcn_mfma_f32_16x16x32_bf16(pa1, vf, o[1][j], 0, 0, 0);
                    }
                }
            }
            asm volatile("" ::: "memory");  // keep ds_reads above the barrier
            __builtin_amdgcn_s_barrier();
            c ^= 1;
        }

        // epilogue: normalize, store bf16 (B,T,H*64)
#pragma unroll
        for (int q16 = 0; q16 < 2; ++q16) {
            float inv = 1.0f / lreg[q16];
#pragma unroll
            for (int r = 0; r < 4; ++r) {
                float ivr = __shfl(inv, lhi * 4 + r);
                int qrow = Q0 + q16 * 16 + lhi * 4 + r;
#pragma unroll
                for (int j = 0; j < 4; ++j)
                    Ob[((size_t)(b * Tc + qrow)) * 2048 + h * 64 + j * 16 + llo] =
                        f2b(o[q16][j][r] * ivr);
            }
        }
    }
}

// ---------------------------------------------------------------------------
extern "C" void kernel_launch(void* const* d_in, const int* in_sizes, int n_in,
                              void* d_out, int out_size, void* d_ws, size_t ws_size,
                              hipStream_t stream) {
    const float* x  = (const float*)d_in[0];
    const float* Wq = (const float*)d_in[1];
    const float* Wk = (const float*)d_in[2];
    const float* Wv = (const float*)d_in[3];
    const float* Wo = (const float*)d_in[4];
    const float* qs = (const float*)d_in[5];
    const float* ks = (const float*)d_in[6];
    float* out = (float*)d_out;

    char* w = (char*)d_ws;
    short* xb   = (short*)(w);                  // 16,777,216  (later: ob)
    short* WqkvT = (short*)(w + 16777216);      // 12,582,912  (3072 x 2048) (later: vt)
    short* WoT  = (short*)(w + 29360128);       //  8,388,608
    short* qkvf = (short*)(w + 37748736);       // 25,165,824  (4096 x 3072)
    short* qb   = (short*)(w + 62914560);       // 16,777,216
    short* kb   = (short*)(w + 79691776);       //  4,194,304
    short* vt   = WqkvT;                        // alias (WqkvT dead after proj gemm)
    short* ob   = xb;                           // alias (xb dead after proj gemm)

    dim3 blk(256);
    // prep: bf16 convert + weight transposes (B^T rows: 0-2047 Wq, 2048-2559 Wk, 2560-3071 Wv)
    convert_x<<<dim3(4096), blk, 0, stream>>>(x, xb);
    tr_w<<<dim3(32, 32), blk, 0, stream>>>(Wq, WqkvT, 2048, 2048);
    tr_w<<<dim3(8, 32), blk, 0, stream>>>(Wk, WqkvT + (size_t)2048 * 2048, 2048, 512);
    tr_w<<<dim3(8, 32), blk, 0, stream>>>(Wv, WqkvT + (size_t)2560 * 2048, 2048, 512);
    tr_w<<<dim3(32, 32), blk, 0, stream>>>(Wo, WoT, 2048, 2048);
    // fused QKV projection (bf16 out, 4096 x 3072, cols 0-2047 q / 2048-2559 k / 2560-3071 v)
    gemm8p<256, short><<<dim3(12, 16), dim3(512), 0, stream>>>(xb, WqkvT, qkvf, 4096, 3072, 2048);
    // RMSNorm + RoPE (+SCALE*log2e on Q) + relayout
    fuse_qk<<<dim3(32768), blk, 0, stream>>>(qkvf, qs, qb, Hc, 3072, QMULT);
    fuse_qk<<<dim3(8192), blk, 0, stream>>>(qkvf + 2048, ks, kb, KVc, 3072, 1.0f);
    fuse_vt<<<dim3(32, 8, 2), blk, 0, stream>>>(qkvf + 2560, vt, 3072);
    // flash attention
    attn_fwd<<<dim3(8, 32, 2), blk, 0, stream>>>(qb, kb, vt, ob);
    // output projection (f32 out, BN=128 for full 256-block fill)
    gemm8p<128, float><<<dim3(16, 16), dim3(512), 0, stream>>>(ob, WoT, out, 4096, 2048, 2048);
}

// Round 9
// 250.785 us; speedup vs baseline: 1.2701x; 1.2701x over previous
//
#include <hip/hip_runtime.h>
#include <hip/hip_bf16.h>

typedef __attribute__((ext_vector_type(4))) float f32x4;
typedef __attribute__((ext_vector_type(8))) short bf16x8;
typedef __attribute__((ext_vector_type(4))) short short4v;

#define DEVI __device__ __forceinline__

constexpr int Bc = 2, Tc = 2048, Dc = 2048, Hc = 32, KVc = 8, HDc = 64;
constexpr int GRP = Hc / KVc;  // 4
constexpr float EPSc = 1e-6f;
// SCALE * log2(e) folded into Q so softmax uses exp2
constexpr float QMULT = 0.125f * 1.4426950408889634f;

DEVI short f2b(float f) {
    __hip_bfloat16 h = __float2bfloat16(f);
    short s;
    __builtin_memcpy(&s, &h, sizeof(short));
    return s;
}
DEVI float b2f(short s) {
    unsigned int u = ((unsigned int)(unsigned short)s) << 16;
    float f;
    __builtin_memcpy(&f, &u, sizeof(float));
    return f;
}

#define GLOAD16(g, l)                                                        \
    __builtin_amdgcn_global_load_lds(                                        \
        (const __attribute__((address_space(1))) void*)(g),                  \
        (__attribute__((address_space(3))) void*)(l), 16, 0, 0)

// ---------------------------------------------------------------------------
// prep: f32 -> bf16 convert (x), each thread 8 elems
// ---------------------------------------------------------------------------
__global__ __launch_bounds__(256) void convert_x(const float* __restrict__ in,
                                                 short* __restrict__ out) {
    size_t i = ((size_t)blockIdx.x * 256 + threadIdx.x) * 8;
    float4 a = *reinterpret_cast<const float4*>(in + i);
    float4 b = *reinterpret_cast<const float4*>(in + i + 4);
    bf16x8 o = {f2b(a.x), f2b(a.y), f2b(a.z), f2b(a.w),
                f2b(b.x), f2b(b.y), f2b(b.z), f2b(b.w)};
    *reinterpret_cast<bf16x8*>(out + i) = o;
}

// ---------------------------------------------------------------------------
// prep: transpose all 4 weights f32 (2048 x C) -> bf16 (C x 2048), one launch.
// grid (32, 32, 4): z selects {Wq, Wk, Wv, Wo}; idle tiles exit.
// ---------------------------------------------------------------------------
__global__ __launch_bounds__(256) void tr_w_all(const float* __restrict__ Wq,
                                                const float* __restrict__ Wk,
                                                const float* __restrict__ Wv,
                                                const float* __restrict__ Wo,
                                                short* __restrict__ WqkvT,
                                                short* __restrict__ WoT) {
    const int z = blockIdx.z;
    const float* src;
    short* dst;
    int C;
    if (z == 0)      { src = Wq; dst = WqkvT;                          C = 2048; }
    else if (z == 1) { src = Wk; dst = WqkvT + (size_t)2048 * 2048;    C = 512; }
    else if (z == 2) { src = Wv; dst = WqkvT + (size_t)2560 * 2048;    C = 512; }
    else             { src = Wo; dst = WoT;                            C = 2048; }
    const int n0 = blockIdx.x * 64, k0 = blockIdx.y * 64;
    if (n0 >= C) return;

    __shared__ __align__(16) short t[64][72];
    const int rl = threadIdx.x >> 2, q = threadIdx.x & 3;
#pragma unroll
    for (int jj = 0; jj < 4; ++jj) {
        float4 v = *reinterpret_cast<const float4*>(src + (size_t)(k0 + rl) * C + n0 + q * 16 + jj * 4);
        short4v s = {f2b(v.x), f2b(v.y), f2b(v.z), f2b(v.w)};
        *reinterpret_cast<short4v*>(&t[rl][q * 16 + jj * 4]) = s;
    }
    __syncthreads();
    alignas(16) short buf[16];
#pragma unroll
    for (int e = 0; e < 16; ++e) buf[e] = t[q * 16 + e][rl];
    short* d = dst + (size_t)(n0 + rl) * 2048 + k0 + q * 16;
    *reinterpret_cast<int4*>(d) = reinterpret_cast<int4*>(buf)[0];
    *reinterpret_cast<int4*>(d + 8) = reinterpret_cast<int4*>(buf)[1];
}

// ---------------------------------------------------------------------------
// GEMM: C(MxN) = A(MxK,bf16 rowmajor) * Bt(NxK,bf16 rowmajor)^T
// 128x128 tile, BK=64, 256 thr (4 waves 2x2), global_load_lds w16 staging,
// double-buffered LDS + counted vmcnt; XOR chunk-swizzle (chunk ^= row&7) via
// pre-swizzled global source so ds_read_b128 is conflict-free.
// ---------------------------------------------------------------------------
template <typename CT>
__global__ __launch_bounds__(256) void gemm_bt(const short* __restrict__ A,
                                               const short* __restrict__ Bt,
                                               CT* __restrict__ C, int M, int N, int K) {
    __shared__ __align__(16) short sA[2][128 * 64];   // 16 KB each buf
    __shared__ __align__(16) short sB[2][128 * 64];

    const int tid = threadIdx.x;
    const int wave = tid >> 6, lane = tid & 63;
    const int lhi = lane >> 4, llo = lane & 15;
    const int bm = blockIdx.y * 128, bn = blockIdx.x * 128;
    const int wm = (wave >> 1) * 64, wn = (wave & 1) * 64;

    // staging: 4 load-rounds per array; chunk id c = l*256+tid in [0,1024)
    // row = c>>3, in-row chunk = c&7, source chunk pre-swizzled by ^(row&7)
    const short* apt[4];
    const short* bpt[4];
#pragma unroll
    for (int l = 0; l < 4; ++l) {
        int c = l * 256 + tid;
        int r = c >> 3, ck = (c & 7) ^ (r & 7);
        apt[l] = A + (size_t)(bm + r) * K + ck * 8;
        bpt[l] = Bt + (size_t)(bn + r) * K + ck * 8;
    }

    f32x4 acc[4][4] = {};

    // prologue: stage K-tile 0 into buf 0
#pragma unroll
    for (int l = 0; l < 4; ++l) {
        GLOAD16(apt[l], &sA[0][(l * 256 + tid) * 8]);
        GLOAD16(bpt[l], &sB[0][(l * 256 + tid) * 8]);
    }
    int c = 0;

    // read-side swizzled chunk offsets (lane-constant): row&7 == llo&7
    const int co0 = ((lhi ^ (llo & 7)) << 3);        // kk=0 chunks 0..3
    const int co1 = (((4 + lhi) ^ (llo & 7)) << 3);  // kk=1 chunks 4..7

#pragma unroll 1
    for (int k0 = 0; k0 < K; k0 += 64) {
        if (k0 + 64 < K) {
            const int kn = k0 + 64;
#pragma unroll
            for (int l = 0; l < 4; ++l) {
                GLOAD16(apt[l] + kn, &sA[c ^ 1][(l * 256 + tid) * 8]);
                GLOAD16(bpt[l] + kn, &sB[c ^ 1][(l * 256 + tid) * 8]);
            }
            asm volatile("s_waitcnt vmcnt(8)" ::: "memory");
        } else {
            asm volatile("s_waitcnt vmcnt(0)" ::: "memory");
        }
        __builtin_amdgcn_s_barrier();
        asm volatile("" ::: "memory");  // keep ds_reads below the barrier

#pragma unroll
        for (int kk = 0; kk < 2; ++kk) {
            const int co = kk ? co1 : co0;
            bf16x8 af[4], bf[4];
#pragma unroll
            for (int i = 0; i < 4; ++i)
                af[i] = *reinterpret_cast<const bf16x8*>(&sA[c][(wm + i * 16 + llo) * 64 + co]);
#pragma unroll
            for (int j = 0; j < 4; ++j)
                bf[j] = *reinterpret_cast<const bf16x8*>(&sB[c][(wn + j * 16 + llo) * 64 + co]);
#pragma unroll
            for (int i = 0; i < 4; ++i)
#pragma unroll
                for (int j = 0; j < 4; ++j)
                    acc[i][j] = __builtin_amdgcn_mfma_f32_16x16x32_bf16(af[i], bf[j], acc[i][j], 0, 0, 0);
        }

        asm volatile("" ::: "memory");  // keep ds_reads above the barrier
        __builtin_amdgcn_s_barrier();
        c ^= 1;
    }

#pragma unroll
    for (int i = 0; i < 4; ++i)
#pragma unroll
        for (int j = 0; j < 4; ++j)
#pragma unroll
            for (int r = 0; r < 4; ++r) {
                size_t idx = (size_t)(bm + wm + i * 16 + lhi * 4 + r) * N + bn + wn + j * 16 + llo;
                if constexpr (sizeof(CT) == 2)
                    C[idx] = f2b(acc[i][j][r]);
                else
                    C[idx] = acc[i][j][r];
            }
}

// ---------------------------------------------------------------------------
// fuse: RMSNorm + RoPE + scale for BOTH q and k in one launch.
// waves [0,131072): q rows (B*T*H); waves [131072,163840): k rows (B*T*KV).
// in stride 3072.  grid 40960 blocks x 256 thr (4 waves each).
// ---------------------------------------------------------------------------
__global__ __launch_bounds__(256) void fuse_qk2(const short* __restrict__ in,
                                                const float* __restrict__ qs,
                                                const float* __restrict__ ks,
                                                short* __restrict__ qout,
                                                short* __restrict__ kout) {
    int wid = (blockIdx.x * 256 + threadIdx.x) >> 6;
    int d = threadIdx.x & 63;
    const bool isq = wid < 131072;
    const int w2 = isq ? wid : wid - 131072;
    const int sh = isq ? 5 : 3;            // log2(Hx)
    const int h = w2 & ((1 << sh) - 1);
    const int bt = w2 >> sh;
    const int t = bt & 2047, b = bt >> 11;

    const int col = (isq ? 0 : 2048) + h * 64 + d;
    float v = b2f(in[(size_t)bt * 3072 + col]);
    float ss = v * v;
#pragma unroll
    for (int m = 1; m < 64; m <<= 1) ss += __shfl_xor(ss, m);
    v = v / sqrtf(ss * (1.0f / 64.0f) + EPSc) * (isq ? qs[d] : ks[d]);

    int i = d & 31;
    float inv_f = exp2f(-0.41524101186092029f * (float)i);  // theta^(-i/32)
    float ang = (float)t * inv_f;
    float sn, cs;
    sincosf(ang, &sn, &cs);
    float other = __shfl_xor(v, 32);
    float o = (d < 32) ? (v * cs - other * sn) : (v * cs + other * sn);
    o *= isq ? QMULT : 1.0f;

    short* out = isq ? qout : kout;
    const int Hx = 1 << sh;
    out[((size_t)(b * Hx + h) * 2048 + t) * 64 + d] = f2b(o);
}

// ---------------------------------------------------------------------------
// fuse: V rows (stride ldin, base pre-offset to V cols) -> transposed tiles
// vt[b][kv][tile][d(64)][t_local(64)].  grid (32 tiles, 8 kv, 2 b)
// ---------------------------------------------------------------------------
__global__ __launch_bounds__(256) void fuse_vt(const short* __restrict__ vsrc,
                                               short* __restrict__ vt, int ldin) {
    __shared__ __align__(16) short t[64][72];
    const int tile = blockIdx.x, kv = blockIdx.y, b = blockIdx.z;
    const int tl = threadIdx.x >> 2, q = threadIdx.x & 3;
    const short* src = vsrc + (size_t)(b * 2048 + tile * 64 + tl) * ldin + kv * 64 + q * 16;
    *reinterpret_cast<bf16x8*>(&t[tl][q * 16]) = *reinterpret_cast<const bf16x8*>(src);
    *reinterpret_cast<bf16x8*>(&t[tl][q * 16 + 8]) = *reinterpret_cast<const bf16x8*>(src + 8);
    __syncthreads();
    alignas(16) short buf[16];
#pragma unroll
    for (int e = 0; e < 16; ++e) buf[e] = t[q * 16 + e][tl];
    short* dst = vt + ((size_t)(b * 8 + kv) * 32 + tile) * 4096 + tl * 64 + q * 16;
    *reinterpret_cast<int4*>(dst) = reinterpret_cast<int4*>(buf)[0];
    *reinterpret_cast<int4*>(dst + 8) = reinterpret_cast<int4*>(buf)[1];
}

// ---------------------------------------------------------------------------
// Flash attention, causal GQA, swapped-QK^T form, double-buffered K/V,
// load-balanced: block p handles q-tiles (15-p) then p  => 34 iters/block.
// grid (8 pairs, 32 h, 2 b); 256 thr = 4 waves, 32 q rows per wave per tile.
// Online softmax with defer-max (T13).
// ---------------------------------------------------------------------------
__global__ __launch_bounds__(256) void attn_fwd(const short* __restrict__ Qb,
                                                const short* __restrict__ Kb,
                                                const short* __restrict__ Vt,
                                                short* __restrict__ Ob) {
    __shared__ __align__(16) short sK[2][64 * 64];
    __shared__ __align__(16) short sV[2][64 * 64];
    __shared__ __align__(16) short sP[4][32 * 72];

    const int pair = blockIdx.x;  // 0..7
    const int h = blockIdx.y, b = blockIdx.z;
    const int kvh = h >> 2;
    const int tid = threadIdx.x, wave = tid >> 6, lane = tid & 63;
    const int lhi = lane >> 4, llo = lane & 15;

    const short* Qp = Qb + (size_t)(b * Hc + h) * Tc * 64;
    const short* Kp = Kb + (size_t)(b * KVc + kvh) * Tc * 64;
    const short* Vp = Vt + (size_t)(b * KVc + kvh) * 32 * 4096;

    // per-thread staging addresses (4 GLOAD16 per tile)
    const int srow0 = tid >> 3, sslot0 = tid & 7;
    const int srow1 = (256 + tid) >> 3, sslot1 = tid & 7;
    const int soff0 = (sslot0 ^ (srow0 & 7)) * 8;
    const int soff1 = (sslot1 ^ (srow1 & 7)) * 8;

#pragma unroll 1
    for (int sub = 0; sub < 2; ++sub) {
        const int qt = sub ? pair : 15 - pair;
        const int Q0 = qt * 128 + wave * 32;
        const int ktmax_w = (Q0 + 31) >> 6;
        const int nkt = 2 * qt + 2;

        bf16x8 qf[2][2];
#pragma unroll
        for (int q16 = 0; q16 < 2; ++q16)
#pragma unroll
            for (int kk = 0; kk < 2; ++kk)
                qf[q16][kk] = *reinterpret_cast<const bf16x8*>(
                    Qp + (size_t)(Q0 + q16 * 16 + llo) * 64 + kk * 32 + lhi * 8);

        f32x4 o[2][4] = {};
        float mreg[2] = {-1e30f, -1e30f};
        float lreg[2] = {0.f, 0.f};

        // prologue: stage tile 0 into buf 0
        {
            GLOAD16(Kp + (size_t)srow0 * 64 + soff0, &sK[0][tid * 8]);
            GLOAD16(Vp + (size_t)srow0 * 64 + soff0, &sV[0][tid * 8]);
            GLOAD16(Kp + (size_t)srow1 * 64 + soff1, &sK[0][(256 + tid) * 8]);
            GLOAD16(Vp + (size_t)srow1 * 64 + soff1, &sV[0][(256 + tid) * 8]);
        }
        int c = 0;

#pragma unroll 1
        for (int kt = 0; kt < nkt; ++kt) {
            const bool has_next = (kt + 1) < nkt;
            if (has_next) {
                const size_t kbase = (size_t)(kt + 1) * 4096;
                GLOAD16(Kp + kbase + srow0 * 64 + soff0, &sK[c ^ 1][tid * 8]);
                GLOAD16(Vp + kbase + srow0 * 64 + soff0, &sV[c ^ 1][tid * 8]);
                GLOAD16(Kp + kbase + srow1 * 64 + soff1, &sK[c ^ 1][(256 + tid) * 8]);
                GLOAD16(Vp + kbase + srow1 * 64 + soff1, &sV[c ^ 1][(256 + tid) * 8]);
                asm volatile("s_waitcnt vmcnt(4)" ::: "memory");
            } else {
                asm volatile("s_waitcnt vmcnt(0)" ::: "memory");
            }
            __builtin_amdgcn_s_barrier();
            asm volatile("" ::: "memory");  // keep ds_reads below the barrier

            if (kt <= ktmax_w) {
                const short* sKc = sK[c];
                const short* sVc = sV[c];
                // S^T = K Q^T : C[kv_local=lhi*4+r][q_local=llo] per (n, q16)
                f32x4 st[2][4];
#pragma unroll
                for (int n = 0; n < 4; ++n) {
                    int krow = n * 16 + llo;
                    bf16x8 ka0 = *reinterpret_cast<const bf16x8*>(
                        &sKc[krow * 64 + ((lhi ^ (krow & 7)) << 3)]);
                    bf16x8 ka1 = *reinterpret_cast<const bf16x8*>(
                        &sKc[krow * 64 + (((4 + lhi) ^ (krow & 7)) << 3)]);
                    f32x4 z = {0.f, 0.f, 0.f, 0.f};
                    st[0][n] = __builtin_amdgcn_mfma_f32_16x16x32_bf16(ka0, qf[0][0], z, 0, 0, 0);
                    st[0][n] = __builtin_amdgcn_mfma_f32_16x16x32_bf16(ka1, qf[0][1], st[0][n], 0, 0, 0);
                    st[1][n] = __builtin_amdgcn_mfma_f32_16x16x32_bf16(ka0, qf[1][0], z, 0, 0, 0);
                    st[1][n] = __builtin_amdgcn_mfma_f32_16x16x32_bf16(ka1, qf[1][1], st[1][n], 0, 0, 0);
                }
                if (kt == ktmax_w) {  // causal mask (diagonal region only)
#pragma unroll
                    for (int q16 = 0; q16 < 2; ++q16) {
                        int qg = Q0 + q16 * 16 + llo;
#pragma unroll
                        for (int n = 0; n < 4; ++n)
#pragma unroll
                            for (int r = 0; r < 4; ++r) {
                                int kvg = kt * 64 + n * 16 + lhi * 4 + r;
                                if (kvg > qg) st[q16][n][r] = -1e30f;
                            }
                    }
                }
                // per-row tile max (lanes sharing llo hold the same row)
                float pm[2];
#pragma unroll
                for (int q16 = 0; q16 < 2; ++q16) {
                    float p = st[q16][0][0];
#pragma unroll
                    for (int n = 0; n < 4; ++n)
#pragma unroll
                        for (int r = 0; r < 4; ++r) p = fmaxf(p, st[q16][n][r]);
                    p = fmaxf(p, __shfl_xor(p, 16));
                    p = fmaxf(p, __shfl_xor(p, 32));
                    pm[q16] = p;
                }
                // defer-max: only rescale when tile max grew past running max + 8
                bool defer = __all((pm[0] - mreg[0] <= 8.f) && (pm[1] - mreg[1] <= 8.f));
                if (!defer) {
                    float alpha[2];
#pragma unroll
                    for (int q16 = 0; q16 < 2; ++q16) {
                        float mn = fmaxf(mreg[q16], pm[q16]);
                        alpha[q16] = __builtin_amdgcn_exp2f(mreg[q16] - mn);
                        mreg[q16] = mn;
                        lreg[q16] *= alpha[q16];
                    }
#pragma unroll
                    for (int q16 = 0; q16 < 2; ++q16)
#pragma unroll
                        for (int r = 0; r < 4; ++r) {
                            float ar = __shfl(alpha[q16], lhi * 4 + r);
#pragma unroll
                            for (int j = 0; j < 4; ++j) o[q16][j][r] *= ar;
                        }
                }
                // P = exp2(S - m); row sums
#pragma unroll
                for (int q16 = 0; q16 < 2; ++q16) {
                    float ps = 0.f;
#pragma unroll
                    for (int n = 0; n < 4; ++n)
#pragma unroll
                        for (int r = 0; r < 4; ++r) {
                            float p = __builtin_amdgcn_exp2f(st[q16][n][r] - mreg[q16]);
                            st[q16][n][r] = p;
                            ps += p;
                        }
                    ps += __shfl_xor(ps, 16);
                    ps += __shfl_xor(ps, 32);
                    lreg[q16] += ps;
                }
                // store P rows to wave-private LDS (b64 stores)
#pragma unroll
                for (int q16 = 0; q16 < 2; ++q16)
#pragma unroll
                    for (int n = 0; n < 4; ++n) {
                        short4v p4 = {f2b(st[q16][n][0]), f2b(st[q16][n][1]),
                                      f2b(st[q16][n][2]), f2b(st[q16][n][3])};
                        *reinterpret_cast<short4v*>(
                            &sP[wave][(q16 * 16 + llo) * 72 + n * 16 + lhi * 4]) = p4;
                    }
                // O += P V
#pragma unroll
                for (int kk = 0; kk < 2; ++kk) {
                    bf16x8 pa0 = *reinterpret_cast<const bf16x8*>(
                        &sP[wave][(0 * 16 + llo) * 72 + kk * 32 + lhi * 8]);
                    bf16x8 pa1 = *reinterpret_cast<const bf16x8*>(
                        &sP[wave][(1 * 16 + llo) * 72 + kk * 32 + lhi * 8]);
#pragma unroll
                    for (int j = 0; j < 4; ++j) {
                        int vrow = j * 16 + llo;
                        bf16x8 vf = *reinterpret_cast<const bf16x8*>(
                            &sVc[vrow * 64 + ((((kk * 4) + lhi) ^ (vrow & 7)) << 3)]);
                        o[0][j] = __builtin_amdgcn_mfma_f32_16x16x32_bf16(pa0, vf, o[0][j], 0, 0, 0);
                        o[1][j] = __builtin_amdgcn_mfma_f32_16x16x32_bf16(pa1, vf, o[1][j], 0, 0, 0);
                    }
                }
            }
            asm volatile("" ::: "memory");  // keep ds_reads above the barrier
            __builtin_amdgcn_s_barrier();
            c ^= 1;
        }

        // epilogue: normalize, store bf16 (B,T,H*64)
#pragma unroll
        for (int q16 = 0; q16 < 2; ++q16) {
            float inv = 1.0f / lreg[q16];
#pragma unroll
            for (int r = 0; r < 4; ++r) {
                float ivr = __shfl(inv, lhi * 4 + r);
                int qrow = Q0 + q16 * 16 + lhi * 4 + r;
#pragma unroll
                for (int j = 0; j < 4; ++j)
                    Ob[((size_t)(b * Tc + qrow)) * 2048 + h * 64 + j * 16 + llo] =
                        f2b(o[q16][j][r] * ivr);
            }
        }
    }
}

// ---------------------------------------------------------------------------
extern "C" void kernel_launch(void* const* d_in, const int* in_sizes, int n_in,
                              void* d_out, int out_size, void* d_ws, size_t ws_size,
                              hipStream_t stream) {
    const float* x  = (const float*)d_in[0];
    const float* Wq = (const float*)d_in[1];
    const float* Wk = (const float*)d_in[2];
    const float* Wv = (const float*)d_in[3];
    const float* Wo = (const float*)d_in[4];
    const float* qs = (const float*)d_in[5];
    const float* ks = (const float*)d_in[6];
    float* out = (float*)d_out;

    char* w = (char*)d_ws;
    short* xb   = (short*)(w);                  // 16,777,216  (later: ob)
    short* WqkvT = (short*)(w + 16777216);      // 12,582,912  (3072 x 2048) (later: vt)
    short* WoT  = (short*)(w + 29360128);       //  8,388,608
    short* qkvf = (short*)(w + 37748736);       // 25,165,824  (4096 x 3072)
    short* qb   = (short*)(w + 62914560);       // 16,777,216
    short* kb   = (short*)(w + 79691776);       //  4,194,304
    short* vt   = WqkvT;                        // alias (WqkvT dead after proj gemm)
    short* ob   = xb;                           // alias (xb dead after proj gemm)

    dim3 blk(256);
    // prep: bf16 convert + all weight transposes in one launch
    convert_x<<<dim3(4096), blk, 0, stream>>>(x, xb);
    tr_w_all<<<dim3(32, 32, 4), blk, 0, stream>>>(Wq, Wk, Wv, Wo, WqkvT, WoT);
    // fused QKV projection (bf16 out, 4096 x 3072, cols 0-2047 q / 2048-2559 k / 2560-3071 v)
    gemm_bt<short><<<dim3(24, 32), blk, 0, stream>>>(xb, WqkvT, qkvf, 4096, 3072, 2048);
    // RMSNorm + RoPE (+SCALE*log2e on Q) + relayout, q and k in one launch
    // q: 131072 waves, k: 32768 waves -> 163840 waves / 4 per block = 40960
    fuse_qk2<<<dim3(40960), blk, 0, stream>>>(qkvf, qs, ks, qb, kb);
    fuse_vt<<<dim3(32, 8, 2), blk, 0, stream>>>(qkvf + 2560, vt, 3072);
    // flash attention
    attn_fwd<<<dim3(8, 32, 2), blk, 0, stream>>>(qb, kb, vt, ob);
    // output projection (f32 out)
    gemm_bt<float><<<dim3(16, 32), blk, 0, stream>>>(ob, WoT, out, 4096, 2048, 2048);
}

// Round 10
// 222.815 us; speedup vs baseline: 1.4296x; 1.1255x over previous
//
#include <hip/hip_runtime.h>
#include <hip/hip_bf16.h>

typedef __attribute__((ext_vector_type(4))) float f32x4;
typedef __attribute__((ext_vector_type(8))) short bf16x8;
typedef __attribute__((ext_vector_type(4))) short short4v;

#define DEVI __device__ __forceinline__

constexpr int Bc = 2, Tc = 2048, Dc = 2048, Hc = 32, KVc = 8, HDc = 64;
constexpr int GRP = Hc / KVc;  // 4
constexpr float EPSc = 1e-6f;
// SCALE * log2(e) folded into Q so softmax uses exp2
constexpr float QMULT = 0.125f * 1.4426950408889634f;
constexpr float INV2PI = 0.15915494309189535f;
constexpr float ROPE_C = 0.41524101186092029f;  // log2(10000)/32

DEVI short f2b(float f) {
    __hip_bfloat16 h = __float2bfloat16(f);
    short s;
    __builtin_memcpy(&s, &h, sizeof(short));
    return s;
}
DEVI float b2f(short s) {
    unsigned int u = ((unsigned int)(unsigned short)s) << 16;
    float f;
    __builtin_memcpy(&f, &u, sizeof(float));
    return f;
}

#define GLOAD16(g, l)                                                        \
    __builtin_amdgcn_global_load_lds(                                        \
        (const __attribute__((address_space(1))) void*)(g),                  \
        (__attribute__((address_space(3))) void*)(l), 16, 0, 0)

// ---------------------------------------------------------------------------
// prep: weight transposes f32 (2048 x C) -> bf16 (C x 2048) (z=0..3) and
// x f32 -> bf16 convert (z=4), one launch.  grid (32, 32, 5).
// ---------------------------------------------------------------------------
__global__ __launch_bounds__(256) void prep_all(const float* __restrict__ x,
                                                const float* __restrict__ Wq,
                                                const float* __restrict__ Wk,
                                                const float* __restrict__ Wv,
                                                const float* __restrict__ Wo,
                                                short* __restrict__ xb,
                                                short* __restrict__ WqkvT,
                                                short* __restrict__ WoT) {
    const int z = blockIdx.z;
    if (z == 4) {  // convert x: 8.4M elems, 1024 blocks, 4 passes of 8/thread
        size_t base = ((size_t)(blockIdx.y * 32 + blockIdx.x) * 256 + threadIdx.x) * 8;
#pragma unroll
        for (int p = 0; p < 4; ++p) {
            size_t i = base + (size_t)p * 2097152;
            float4 a = *reinterpret_cast<const float4*>(x + i);
            float4 b = *reinterpret_cast<const float4*>(x + i + 4);
            bf16x8 o = {f2b(a.x), f2b(a.y), f2b(a.z), f2b(a.w),
                        f2b(b.x), f2b(b.y), f2b(b.z), f2b(b.w)};
            *reinterpret_cast<bf16x8*>(xb + i) = o;
        }
        return;
    }
    const float* src;
    short* dst;
    int C;
    if (z == 0)      { src = Wq; dst = WqkvT;                          C = 2048; }
    else if (z == 1) { src = Wk; dst = WqkvT + (size_t)2048 * 2048;    C = 512; }
    else if (z == 2) { src = Wv; dst = WqkvT + (size_t)2560 * 2048;    C = 512; }
    else             { src = Wo; dst = WoT;                            C = 2048; }
    const int n0 = blockIdx.x * 64, k0 = blockIdx.y * 64;
    if (n0 >= C) return;

    __shared__ __align__(16) short t[64][72];
    const int rl = threadIdx.x >> 2, q = threadIdx.x & 3;
#pragma unroll
    for (int jj = 0; jj < 4; ++jj) {
        float4 v = *reinterpret_cast<const float4*>(src + (size_t)(k0 + rl) * C + n0 + q * 16 + jj * 4);
        short4v s = {f2b(v.x), f2b(v.y), f2b(v.z), f2b(v.w)};
        *reinterpret_cast<short4v*>(&t[rl][q * 16 + jj * 4]) = s;
    }
    __syncthreads();
    alignas(16) short buf[16];
#pragma unroll
    for (int e = 0; e < 16; ++e) buf[e] = t[q * 16 + e][rl];
    short* d = dst + (size_t)(n0 + rl) * 2048 + k0 + q * 16;
    *reinterpret_cast<int4*>(d) = reinterpret_cast<int4*>(buf)[0];
    *reinterpret_cast<int4*>(d + 8) = reinterpret_cast<int4*>(buf)[1];
}

// bijective XCD swizzle of flattened block id (nwg % 8 == 0)
DEVI void xcd_swizzle(int nx, int& bx, int& by) {
    int nwg = nx * gridDim.y;
    int fb = by * nx + bx;
    int cpx = nwg >> 3;
    int swz = (fb & 7) * cpx + (fb >> 3);
    by = swz / nx;
    bx = swz - by * nx;
}

// ---------------------------------------------------------------------------
// QKV-projection GEMM with fused RMSNorm+RoPE epilogue.
// C(4096x3072) = xb(4096x2048) * WqkvT(3072x2048)^T, 128x128 tile, BK=64,
// 256 thr (4 waves 2x2 of 64x64).  Each wave's 64 output cols = one head.
// Epilogue: cols<2048 -> RMSNorm(qs)+RoPE+QMULT -> qb (B,H,T,64)
//           cols 2048-2559 -> RMSNorm(ks)+RoPE -> kb (B,KV,T,64)
//           cols>=2560 -> raw bf16 -> vslab (4096 x 512 row-major)
// ---------------------------------------------------------------------------
__global__ __launch_bounds__(256) void gemm_proj(const short* __restrict__ A,
                                                 const short* __restrict__ Bt,
                                                 const float* __restrict__ qs,
                                                 const float* __restrict__ ks,
                                                 short* __restrict__ qb,
                                                 short* __restrict__ kb,
                                                 short* __restrict__ vslab) {
    constexpr int K = 2048;
    __shared__ __align__(16) short sA[2][128 * 64];
    __shared__ __align__(16) short sB[2][128 * 64];

    const int tid = threadIdx.x;
    const int wave = tid >> 6, lane = tid & 63;
    const int lhi = lane >> 4, llo = lane & 15;
    int bx = blockIdx.x, by = blockIdx.y;
    xcd_swizzle(24, bx, by);
    const int bm = by * 128, bn = bx * 128;
    const int wm = (wave >> 1) * 64, wn = (wave & 1) * 64;

    const short* apt[4];
    const short* bpt[4];
#pragma unroll
    for (int l = 0; l < 4; ++l) {
        int c = l * 256 + tid;
        int r = c >> 3, ck = (c & 7) ^ (r & 7);
        apt[l] = A + (size_t)(bm + r) * K + ck * 8;
        bpt[l] = Bt + (size_t)(bn + r) * K + ck * 8;
    }

    f32x4 acc[4][4] = {};

#pragma unroll
    for (int l = 0; l < 4; ++l) {
        GLOAD16(apt[l], &sA[0][(l * 256 + tid) * 8]);
        GLOAD16(bpt[l], &sB[0][(l * 256 + tid) * 8]);
    }
    int c = 0;
    const int co0 = ((lhi ^ (llo & 7)) << 3);
    const int co1 = (((4 + lhi) ^ (llo & 7)) << 3);

#pragma unroll 1
    for (int k0 = 0; k0 < K; k0 += 64) {
        if (k0 + 64 < K) {
            const int kn = k0 + 64;
#pragma unroll
            for (int l = 0; l < 4; ++l) {
                GLOAD16(apt[l] + kn, &sA[c ^ 1][(l * 256 + tid) * 8]);
                GLOAD16(bpt[l] + kn, &sB[c ^ 1][(l * 256 + tid) * 8]);
            }
            asm volatile("s_waitcnt vmcnt(8)" ::: "memory");
        } else {
            asm volatile("s_waitcnt vmcnt(0)" ::: "memory");
        }
        __builtin_amdgcn_s_barrier();
        asm volatile("" ::: "memory");

#pragma unroll
        for (int kk = 0; kk < 2; ++kk) {
            const int co = kk ? co1 : co0;
            bf16x8 af[4], bf[4];
#pragma unroll
            for (int i = 0; i < 4; ++i)
                af[i] = *reinterpret_cast<const bf16x8*>(&sA[c][(wm + i * 16 + llo) * 64 + co]);
#pragma unroll
            for (int j = 0; j < 4; ++j)
                bf[j] = *reinterpret_cast<const bf16x8*>(&sB[c][(wn + j * 16 + llo) * 64 + co]);
#pragma unroll
            for (int i = 0; i < 4; ++i)
#pragma unroll
                for (int j = 0; j < 4; ++j)
                    acc[i][j] = __builtin_amdgcn_mfma_f32_16x16x32_bf16(af[i], bf[j], acc[i][j], 0, 0, 0);
        }

        asm volatile("" ::: "memory");
        __builtin_amdgcn_s_barrier();
        c ^= 1;
    }

    // ---- fused epilogue ----
    const int rm = bm + wm;       // wave's first output row
    const int b = rm >> 11;
    const int tb = rm & 2047;
    const int col0 = bn + wn;     // wave's first output col (64-aligned)

    if (col0 < 2560) {
        const bool isq = col0 < 2048;
        const float* scale = isq ? qs : ks;
        const float mult = isq ? QMULT : 1.0f;
        float scl[4];
#pragma unroll
        for (int j = 0; j < 4; ++j) scl[j] = scale[j * 16 + llo];
        short* outp;
        if (isq)
            outp = qb + (size_t)(b * Hc + (col0 >> 6)) * 2048 * 64;
        else
            outp = kb + (size_t)(b * KVc + ((col0 - 2048) >> 6)) * 2048 * 64;
        // per-lane RoPE revolution factors: i_rope = (j&1)*16 + llo
        const float ir0 = INV2PI * exp2f(-ROPE_C * (float)llo);
        const float ir1 = INV2PI * exp2f(-ROPE_C * (float)(16 + llo));
#pragma unroll
        for (int i = 0; i < 4; ++i)
#pragma unroll
            for (int r = 0; r < 4; ++r) {
                float ss = 0.f;
#pragma unroll
                for (int j = 0; j < 4; ++j) ss += acc[i][j][r] * acc[i][j][r];
                ss += __shfl_xor(ss, 1);
                ss += __shfl_xor(ss, 2);
                ss += __shfl_xor(ss, 4);
                ss += __shfl_xor(ss, 8);
                float rinv = 1.0f / sqrtf(ss * (1.0f / 64.0f) + EPSc);
                float vn[4];
#pragma unroll
                for (int j = 0; j < 4; ++j) vn[j] = acc[i][j][r] * rinv * scl[j];
                const int t = tb + i * 16 + lhi * 4 + r;
                float f0 = (float)t * ir0;
                f0 -= floorf(f0);
                float f1 = (float)t * ir1;
                f1 -= floorf(f1);
                float sn0 = __builtin_amdgcn_sinf(f0), cs0 = __builtin_amdgcn_cosf(f0);
                float sn1 = __builtin_amdgcn_sinf(f1), cs1 = __builtin_amdgcn_cosf(f1);
                size_t base = (size_t)t * 64 + llo;
                outp[base]      = f2b((vn[0] * cs0 - vn[2] * sn0) * mult);
                outp[base + 16] = f2b((vn[1] * cs1 - vn[3] * sn1) * mult);
                outp[base + 32] = f2b((vn[2] * cs0 + vn[0] * sn0) * mult);
                outp[base + 48] = f2b((vn[3] * cs1 + vn[1] * sn1) * mult);
            }
    } else {
        const int cb = col0 - 2560;
#pragma unroll
        for (int i = 0; i < 4; ++i)
#pragma unroll
            for (int j = 0; j < 4; ++j)
#pragma unroll
                for (int r = 0; r < 4; ++r)
                    vslab[(size_t)(rm + i * 16 + lhi * 4 + r) * 512 + cb + j * 16 + llo] =
                        f2b(acc[i][j][r]);
    }
}

// ---------------------------------------------------------------------------
// GEMM: C(MxN) = A(MxK,bf16) * Bt(NxK,bf16)^T  (used for output projection)
// 128x128 tile, BK=64, dbuf + counted vmcnt + XOR chunk-swizzle.
// ---------------------------------------------------------------------------
template <typename CT>
__global__ __launch_bounds__(256) void gemm_bt(const short* __restrict__ A,
                                               const short* __restrict__ Bt,
                                               CT* __restrict__ C, int M, int N, int K) {
    __shared__ __align__(16) short sA[2][128 * 64];
    __shared__ __align__(16) short sB[2][128 * 64];

    const int tid = threadIdx.x;
    const int wave = tid >> 6, lane = tid & 63;
    const int lhi = lane >> 4, llo = lane & 15;
    int bx = blockIdx.x, by = blockIdx.y;
    xcd_swizzle(gridDim.x, bx, by);
    const int bm = by * 128, bn = bx * 128;
    const int wm = (wave >> 1) * 64, wn = (wave & 1) * 64;

    const short* apt[4];
    const short* bpt[4];
#pragma unroll
    for (int l = 0; l < 4; ++l) {
        int c = l * 256 + tid;
        int r = c >> 3, ck = (c & 7) ^ (r & 7);
        apt[l] = A + (size_t)(bm + r) * K + ck * 8;
        bpt[l] = Bt + (size_t)(bn + r) * K + ck * 8;
    }

    f32x4 acc[4][4] = {};

#pragma unroll
    for (int l = 0; l < 4; ++l) {
        GLOAD16(apt[l], &sA[0][(l * 256 + tid) * 8]);
        GLOAD16(bpt[l], &sB[0][(l * 256 + tid) * 8]);
    }
    int c = 0;
    const int co0 = ((lhi ^ (llo & 7)) << 3);
    const int co1 = (((4 + lhi) ^ (llo & 7)) << 3);

#pragma unroll 1
    for (int k0 = 0; k0 < K; k0 += 64) {
        if (k0 + 64 < K) {
            const int kn = k0 + 64;
#pragma unroll
            for (int l = 0; l < 4; ++l) {
                GLOAD16(apt[l] + kn, &sA[c ^ 1][(l * 256 + tid) * 8]);
                GLOAD16(bpt[l] + kn, &sB[c ^ 1][(l * 256 + tid) * 8]);
            }
            asm volatile("s_waitcnt vmcnt(8)" ::: "memory");
        } else {
            asm volatile("s_waitcnt vmcnt(0)" ::: "memory");
        }
        __builtin_amdgcn_s_barrier();
        asm volatile("" ::: "memory");

#pragma unroll
        for (int kk = 0; kk < 2; ++kk) {
            const int co = kk ? co1 : co0;
            bf16x8 af[4], bf[4];
#pragma unroll
            for (int i = 0; i < 4; ++i)
                af[i] = *reinterpret_cast<const bf16x8*>(&sA[c][(wm + i * 16 + llo) * 64 + co]);
#pragma unroll
            for (int j = 0; j < 4; ++j)
                bf[j] = *reinterpret_cast<const bf16x8*>(&sB[c][(wn + j * 16 + llo) * 64 + co]);
#pragma unroll
            for (int i = 0; i < 4; ++i)
#pragma unroll
                for (int j = 0; j < 4; ++j)
                    acc[i][j] = __builtin_amdgcn_mfma_f32_16x16x32_bf16(af[i], bf[j], acc[i][j], 0, 0, 0);
        }

        asm volatile("" ::: "memory");
        __builtin_amdgcn_s_barrier();
        c ^= 1;
    }

#pragma unroll
    for (int i = 0; i < 4; ++i)
#pragma unroll
        for (int j = 0; j < 4; ++j)
#pragma unroll
            for (int r = 0; r < 4; ++r) {
                size_t idx = (size_t)(bm + wm + i * 16 + lhi * 4 + r) * N + bn + wn + j * 16 + llo;
                if constexpr (sizeof(CT) == 2)
                    C[idx] = f2b(acc[i][j][r]);
                else
                    C[idx] = acc[i][j][r];
            }
}

// ---------------------------------------------------------------------------
// fuse: V rows (vslab 4096 x 512) -> transposed tiles
// vt[b][kv][tile][d(64)][t_local(64)].  grid (32 tiles, 8 kv, 2 b)
// ---------------------------------------------------------------------------
__global__ __launch_bounds__(256) void fuse_vt(const short* __restrict__ vsrc,
                                               short* __restrict__ vt, int ldin) {
    __shared__ __align__(16) short t[64][72];
    const int tile = blockIdx.x, kv = blockIdx.y, b = blockIdx.z;
    const int tl = threadIdx.x >> 2, q = threadIdx.x & 3;
    const short* src = vsrc + (size_t)(b * 2048 + tile * 64 + tl) * ldin + kv * 64 + q * 16;
    *reinterpret_cast<bf16x8*>(&t[tl][q * 16]) = *reinterpret_cast<const bf16x8*>(src);
    *reinterpret_cast<bf16x8*>(&t[tl][q * 16 + 8]) = *reinterpret_cast<const bf16x8*>(src + 8);
    __syncthreads();
    alignas(16) short buf[16];
#pragma unroll
    for (int e = 0; e < 16; ++e) buf[e] = t[q * 16 + e][tl];
    short* dst = vt + ((size_t)(b * 8 + kv) * 32 + tile) * 4096 + tl * 64 + q * 16;
    *reinterpret_cast<int4*>(dst) = reinterpret_cast<int4*>(buf)[0];
    *reinterpret_cast<int4*>(dst + 8) = reinterpret_cast<int4*>(buf)[1];
}

// ---------------------------------------------------------------------------
// Flash attention, causal GQA, swapped-QK^T form, double-buffered K/V,
// load-balanced pairing, defer-max online softmax. grid (8, 32, 2), 256 thr.
// ---------------------------------------------------------------------------
__global__ __launch_bounds__(256) void attn_fwd(const short* __restrict__ Qb,
                                                const short* __restrict__ Kb,
                                                const short* __restrict__ Vt,
                                                short* __restrict__ Ob) {
    __shared__ __align__(16) short sK[2][64 * 64];
    __shared__ __align__(16) short sV[2][64 * 64];
    __shared__ __align__(16) short sP[4][32 * 72];

    const int pair = blockIdx.x;
    const int h = blockIdx.y, b = blockIdx.z;
    const int kvh = h >> 2;
    const int tid = threadIdx.x, wave = tid >> 6, lane = tid & 63;
    const int lhi = lane >> 4, llo = lane & 15;

    const short* Qp = Qb + (size_t)(b * Hc + h) * Tc * 64;
    const short* Kp = Kb + (size_t)(b * KVc + kvh) * Tc * 64;
    const short* Vp = Vt + (size_t)(b * KVc + kvh) * 32 * 4096;

    const int srow0 = tid >> 3, sslot0 = tid & 7;
    const int srow1 = (256 + tid) >> 3, sslot1 = tid & 7;
    const int soff0 = (sslot0 ^ (srow0 & 7)) * 8;
    const int soff1 = (sslot1 ^ (srow1 & 7)) * 8;

#pragma unroll 1
    for (int sub = 0; sub < 2; ++sub) {
        const int qt = sub ? pair : 15 - pair;
        const int Q0 = qt * 128 + wave * 32;
        const int ktmax_w = (Q0 + 31) >> 6;
        const int nkt = 2 * qt + 2;

        bf16x8 qf[2][2];
#pragma unroll
        for (int q16 = 0; q16 < 2; ++q16)
#pragma unroll
            for (int kk = 0; kk < 2; ++kk)
                qf[q16][kk] = *reinterpret_cast<const bf16x8*>(
                    Qp + (size_t)(Q0 + q16 * 16 + llo) * 64 + kk * 32 + lhi * 8);

        f32x4 o[2][4] = {};
        float mreg[2] = {-1e30f, -1e30f};
        float lreg[2] = {0.f, 0.f};

        {
            GLOAD16(Kp + (size_t)srow0 * 64 + soff0, &sK[0][tid * 8]);
            GLOAD16(Vp + (size_t)srow0 * 64 + soff0, &sV[0][tid * 8]);
            GLOAD16(Kp + (size_t)srow1 * 64 + soff1, &sK[0][(256 + tid) * 8]);
            GLOAD16(Vp + (size_t)srow1 * 64 + soff1, &sV[0][(256 + tid) * 8]);
        }
        int c = 0;

#pragma unroll 1
        for (int kt = 0; kt < nkt; ++kt) {
            const bool has_next = (kt + 1) < nkt;
            if (has_next) {
                const size_t kbase = (size_t)(kt + 1) * 4096;
                GLOAD16(Kp + kbase + srow0 * 64 + soff0, &sK[c ^ 1][tid * 8]);
                GLOAD16(Vp + kbase + srow0 * 64 + soff0, &sV[c ^ 1][tid * 8]);
                GLOAD16(Kp + kbase + srow1 * 64 + soff1, &sK[c ^ 1][(256 + tid) * 8]);
                GLOAD16(Vp + kbase + srow1 * 64 + soff1, &sV[c ^ 1][(256 + tid) * 8]);
                asm volatile("s_waitcnt vmcnt(4)" ::: "memory");
            } else {
                asm volatile("s_waitcnt vmcnt(0)" ::: "memory");
            }
            __builtin_amdgcn_s_barrier();
            asm volatile("" ::: "memory");

            if (kt <= ktmax_w) {
                const short* sKc = sK[c];
                const short* sVc = sV[c];
                f32x4 st[2][4];
#pragma unroll
                for (int n = 0; n < 4; ++n) {
                    int krow = n * 16 + llo;
                    bf16x8 ka0 = *reinterpret_cast<const bf16x8*>(
                        &sKc[krow * 64 + ((lhi ^ (krow & 7)) << 3)]);
                    bf16x8 ka1 = *reinterpret_cast<const bf16x8*>(
                        &sKc[krow * 64 + (((4 + lhi) ^ (krow & 7)) << 3)]);
                    f32x4 z = {0.f, 0.f, 0.f, 0.f};
                    st[0][n] = __builtin_amdgcn_mfma_f32_16x16x32_bf16(ka0, qf[0][0], z, 0, 0, 0);
                    st[0][n] = __builtin_amdgcn_mfma_f32_16x16x32_bf16(ka1, qf[0][1], st[0][n], 0, 0, 0);
                    st[1][n] = __builtin_amdgcn_mfma_f32_16x16x32_bf16(ka0, qf[1][0], z, 0, 0, 0);
                    st[1][n] = __builtin_amdgcn_mfma_f32_16x16x32_bf16(ka1, qf[1][1], st[1][n], 0, 0, 0);
                }
                if (kt == ktmax_w) {
#pragma unroll
                    for (int q16 = 0; q16 < 2; ++q16) {
                        int qg = Q0 + q16 * 16 + llo;
#pragma unroll
                        for (int n = 0; n < 4; ++n)
#pragma unroll
                            for (int r = 0; r < 4; ++r) {
                                int kvg = kt * 64 + n * 16 + lhi * 4 + r;
                                if (kvg > qg) st[q16][n][r] = -1e30f;
                            }
                    }
                }
                float pm[2];
#pragma unroll
                for (int q16 = 0; q16 < 2; ++q16) {
                    float p = st[q16][0][0];
#pragma unroll
                    for (int n = 0; n < 4; ++n)
#pragma unroll
                        for (int r = 0; r < 4; ++r) p = fmaxf(p, st[q16][n][r]);
                    p = fmaxf(p, __shfl_xor(p, 16));
                    p = fmaxf(p, __shfl_xor(p, 32));
                    pm[q16] = p;
                }
                bool defer = __all((pm[0] - mreg[0] <= 8.f) && (pm[1] - mreg[1] <= 8.f));
                if (!defer) {
                    float alpha[2];
#pragma unroll
                    for (int q16 = 0; q16 < 2; ++q16) {
                        float mn = fmaxf(mreg[q16], pm[q16]);
                        alpha[q16] = __builtin_amdgcn_exp2f(mreg[q16] - mn);
                        mreg[q16] = mn;
                        lreg[q16] *= alpha[q16];
                    }
#pragma unroll
                    for (int q16 = 0; q16 < 2; ++q16)
#pragma unroll
                        for (int r = 0; r < 4; ++r) {
                            float ar = __shfl(alpha[q16], lhi * 4 + r);
#pragma unroll
                            for (int j = 0; j < 4; ++j) o[q16][j][r] *= ar;
                        }
                }
#pragma unroll
                for (int q16 = 0; q16 < 2; ++q16) {
                    float ps = 0.f;
#pragma unroll
                    for (int n = 0; n < 4; ++n)
#pragma unroll
                        for (int r = 0; r < 4; ++r) {
                            float p = __builtin_amdgcn_exp2f(st[q16][n][r] - mreg[q16]);
                            st[q16][n][r] = p;
                            ps += p;
                        }
                    ps += __shfl_xor(ps, 16);
                    ps += __shfl_xor(ps, 32);
                    lreg[q16] += ps;
                }
#pragma unroll
                for (int q16 = 0; q16 < 2; ++q16)
#pragma unroll
                    for (int n = 0; n < 4; ++n) {
                        short4v p4 = {f2b(st[q16][n][0]), f2b(st[q16][n][1]),
                                      f2b(st[q16][n][2]), f2b(st[q16][n][3])};
                        *reinterpret_cast<short4v*>(
                            &sP[wave][(q16 * 16 + llo) * 72 + n * 16 + lhi * 4]) = p4;
                    }
#pragma unroll
                for (int kk = 0; kk < 2; ++kk) {
                    bf16x8 pa0 = *reinterpret_cast<const bf16x8*>(
                        &sP[wave][(0 * 16 + llo) * 72 + kk * 32 + lhi * 8]);
                    bf16x8 pa1 = *reinterpret_cast<const bf16x8*>(
                        &sP[wave][(1 * 16 + llo) * 72 + kk * 32 + lhi * 8]);
#pragma unroll
                    for (int j = 0; j < 4; ++j) {
                        int vrow = j * 16 + llo;
                        bf16x8 vf = *reinterpret_cast<const bf16x8*>(
                            &sVc[vrow * 64 + ((((kk * 4) + lhi) ^ (vrow & 7)) << 3)]);
                        o[0][j] = __builtin_amdgcn_mfma_f32_16x16x32_bf16(pa0, vf, o[0][j], 0, 0, 0);
                        o[1][j] = __builtin_amdgcn_mfma_f32_16x16x32_bf16(pa1, vf, o[1][j], 0, 0, 0);
                    }
                }
            }
            asm volatile("" ::: "memory");
            __builtin_amdgcn_s_barrier();
            c ^= 1;
        }

#pragma unroll
        for (int q16 = 0; q16 < 2; ++q16) {
            float inv = 1.0f / lreg[q16];
#pragma unroll
            for (int r = 0; r < 4; ++r) {
                float ivr = __shfl(inv, lhi * 4 + r);
                int qrow = Q0 + q16 * 16 + lhi * 4 + r;
#pragma unroll
                for (int j = 0; j < 4; ++j)
                    Ob[((size_t)(b * Tc + qrow)) * 2048 + h * 64 + j * 16 + llo] =
                        f2b(o[q16][j][r] * ivr);
            }
        }
    }
}

// ---------------------------------------------------------------------------
extern "C" void kernel_launch(void* const* d_in, const int* in_sizes, int n_in,
                              void* d_out, int out_size, void* d_ws, size_t ws_size,
                              hipStream_t stream) {
    const float* x  = (const float*)d_in[0];
    const float* Wq = (const float*)d_in[1];
    const float* Wk = (const float*)d_in[2];
    const float* Wv = (const float*)d_in[3];
    const float* Wo = (const float*)d_in[4];
    const float* qs = (const float*)d_in[5];
    const float* ks = (const float*)d_in[6];
    float* out = (float*)d_out;

    char* w = (char*)d_ws;
    short* xb    = (short*)(w);                 // 16,777,216  (later: ob)
    short* WqkvT = (short*)(w + 16777216);      // 12,582,912  (later: vt)
    short* WoT   = (short*)(w + 29360128);      //  8,388,608
    short* vslab = (short*)(w + 37748736);      //  4,194,304  (4096 x 512)
    short* qb    = (short*)(w + 62914560);      // 16,777,216
    short* kb    = (short*)(w + 79691776);      //  4,194,304
    short* vt    = WqkvT;                       // alias (WqkvT dead after proj)
    short* ob    = xb;                          // alias (xb dead after proj)

    dim3 blk(256);
    // prep: x convert + all weight transposes in one launch
    prep_all<<<dim3(32, 32, 5), blk, 0, stream>>>(x, Wq, Wk, Wv, Wo, xb, WqkvT, WoT);
    // fused QKV projection + RMSNorm + RoPE epilogue -> qb, kb, vslab
    gemm_proj<<<dim3(24, 32), blk, 0, stream>>>(xb, WqkvT, qs, ks, qb, kb, vslab);
    // V transpose tiles
    fuse_vt<<<dim3(32, 8, 2), blk, 0, stream>>>(vslab, vt, 512);
    // flash attention
    attn_fwd<<<dim3(8, 32, 2), blk, 0, stream>>>(qb, kb, vt, ob);
    // output projection (f32 out)
    gemm_bt<float><<<dim3(16, 32), blk, 0, stream>>>(ob, WoT, out, 4096, 2048, 2048);
}

// Round 11
// 220.049 us; speedup vs baseline: 1.4476x; 1.0126x over previous
//
#include <hip/hip_runtime.h>
#include <hip/hip_bf16.h>

typedef __attribute__((ext_vector_type(4))) float f32x4;
typedef __attribute__((ext_vector_type(8))) short bf16x8;
typedef __attribute__((ext_vector_type(4))) short short4v;

#define DEVI __device__ __forceinline__

constexpr int Bc = 2, Tc = 2048, Dc = 2048, Hc = 32, KVc = 8, HDc = 64;
constexpr int GRP = Hc / KVc;  // 4
constexpr float EPSc = 1e-6f;
// SCALE * log2(e) folded into Q so softmax uses exp2
constexpr float QMULT = 0.125f * 1.4426950408889634f;
constexpr float INV2PI = 0.15915494309189535f;
constexpr float ROPE_C = 0.41524101186092029f;  // log2(10000)/32

DEVI short f2b(float f) {
    __hip_bfloat16 h = __float2bfloat16(f);
    short s;
    __builtin_memcpy(&s, &h, sizeof(short));
    return s;
}
DEVI float b2f(short s) {
    unsigned int u = ((unsigned int)(unsigned short)s) << 16;
    float f;
    __builtin_memcpy(&f, &u, sizeof(float));
    return f;
}

#define GLOAD16(g, l)                                                        \
    __builtin_amdgcn_global_load_lds(                                        \
        (const __attribute__((address_space(1))) void*)(g),                  \
        (__attribute__((address_space(3))) void*)(l), 16, 0, 0)

// ---------------------------------------------------------------------------
// prep: weight transposes f32 (2048 x C) -> bf16 (C x 2048) (z=0..3) and
// x f32 -> bf16 convert (z=4), one launch.  grid (32, 32, 5).
// ---------------------------------------------------------------------------
__global__ __launch_bounds__(256) void prep_all(const float* __restrict__ x,
                                                const float* __restrict__ Wq,
                                                const float* __restrict__ Wk,
                                                const float* __restrict__ Wv,
                                                const float* __restrict__ Wo,
                                                short* __restrict__ xb,
                                                short* __restrict__ WqkvT,
                                                short* __restrict__ WoT) {
    const int z = blockIdx.z;
    if (z == 4) {  // convert x: 8.4M elems, 1024 blocks, 4 passes of 8/thread
        size_t base = ((size_t)(blockIdx.y * 32 + blockIdx.x) * 256 + threadIdx.x) * 8;
#pragma unroll
        for (int p = 0; p < 4; ++p) {
            size_t i = base + (size_t)p * 2097152;
            float4 a = *reinterpret_cast<const float4*>(x + i);
            float4 b = *reinterpret_cast<const float4*>(x + i + 4);
            bf16x8 o = {f2b(a.x), f2b(a.y), f2b(a.z), f2b(a.w),
                        f2b(b.x), f2b(b.y), f2b(b.z), f2b(b.w)};
            *reinterpret_cast<bf16x8*>(xb + i) = o;
        }
        return;
    }
    const float* src;
    short* dst;
    int C;
    if (z == 0)      { src = Wq; dst = WqkvT;                          C = 2048; }
    else if (z == 1) { src = Wk; dst = WqkvT + (size_t)2048 * 2048;    C = 512; }
    else if (z == 2) { src = Wv; dst = WqkvT + (size_t)2560 * 2048;    C = 512; }
    else             { src = Wo; dst = WoT;                            C = 2048; }
    const int n0 = blockIdx.x * 64, k0 = blockIdx.y * 64;
    if (n0 >= C) return;

    __shared__ __align__(16) short t[64][72];
    const int rl = threadIdx.x >> 2, q = threadIdx.x & 3;
#pragma unroll
    for (int jj = 0; jj < 4; ++jj) {
        float4 v = *reinterpret_cast<const float4*>(src + (size_t)(k0 + rl) * C + n0 + q * 16 + jj * 4);
        short4v s = {f2b(v.x), f2b(v.y), f2b(v.z), f2b(v.w)};
        *reinterpret_cast<short4v*>(&t[rl][q * 16 + jj * 4]) = s;
    }
    __syncthreads();
    alignas(16) short buf[16];
#pragma unroll
    for (int e = 0; e < 16; ++e) buf[e] = t[q * 16 + e][rl];
    short* d = dst + (size_t)(n0 + rl) * 2048 + k0 + q * 16;
    *reinterpret_cast<int4*>(d) = reinterpret_cast<int4*>(buf)[0];
    *reinterpret_cast<int4*>(d + 8) = reinterpret_cast<int4*>(buf)[1];
}

// bijective XCD swizzle of flattened block id (nwg % 8 == 0)
DEVI void xcd_swizzle(int nx, int& bx, int& by) {
    int nwg = nx * gridDim.y;
    int fb = by * nx + bx;
    int cpx = nwg >> 3;
    int swz = (fb & 7) * cpx + (fb >> 3);
    by = swz / nx;
    bx = swz - by * nx;
}

// ---------------------------------------------------------------------------
// QKV-projection GEMM with fused RMSNorm+RoPE epilogue and fused V-transpose.
// C(4096x3072) = xb(4096x2048) * WqkvT(3072x2048)^T, 128x128 tile, BK=64,
// 256 thr (4 waves 2x2 of 64x64).  Each wave's 64 output cols = one head.
// Epilogue: cols<2048 -> RMSNorm(qs)+RoPE+QMULT -> qb (B,H,T,64)
//           cols 2048-2559 -> RMSNorm(ks)+RoPE -> kb (B,KV,T,64)
//           cols>=2560 -> transposed bf16 tiles vt[b][kv][tile][d64][t64]
// ---------------------------------------------------------------------------
__global__ __launch_bounds__(256) void gemm_proj(const short* __restrict__ A,
                                                 const short* __restrict__ Bt,
                                                 const float* __restrict__ qs,
                                                 const float* __restrict__ ks,
                                                 short* __restrict__ qb,
                                                 short* __restrict__ kb,
                                                 short* __restrict__ vt) {
    constexpr int K = 2048;
    __shared__ __align__(16) short sA[2][128 * 64];
    __shared__ __align__(16) short sB[2][128 * 64];

    const int tid = threadIdx.x;
    const int wave = tid >> 6, lane = tid & 63;
    const int lhi = lane >> 4, llo = lane & 15;
    int bx = blockIdx.x, by = blockIdx.y;
    xcd_swizzle(24, bx, by);
    const int bm = by * 128, bn = bx * 128;
    const int wm = (wave >> 1) * 64, wn = (wave & 1) * 64;

    const short* apt[4];
    const short* bpt[4];
#pragma unroll
    for (int l = 0; l < 4; ++l) {
        int c = l * 256 + tid;
        int r = c >> 3, ck = (c & 7) ^ (r & 7);
        apt[l] = A + (size_t)(bm + r) * K + ck * 8;
        bpt[l] = Bt + (size_t)(bn + r) * K + ck * 8;
    }

    f32x4 acc[4][4] = {};

#pragma unroll
    for (int l = 0; l < 4; ++l) {
        GLOAD16(apt[l], &sA[0][(l * 256 + tid) * 8]);
        GLOAD16(bpt[l], &sB[0][(l * 256 + tid) * 8]);
    }
    int c = 0;
    const int co0 = ((lhi ^ (llo & 7)) << 3);
    const int co1 = (((4 + lhi) ^ (llo & 7)) << 3);

#pragma unroll 1
    for (int k0 = 0; k0 < K; k0 += 64) {
        if (k0 + 64 < K) {
            const int kn = k0 + 64;
#pragma unroll
            for (int l = 0; l < 4; ++l) {
                GLOAD16(apt[l] + kn, &sA[c ^ 1][(l * 256 + tid) * 8]);
                GLOAD16(bpt[l] + kn, &sB[c ^ 1][(l * 256 + tid) * 8]);
            }
            asm volatile("s_waitcnt vmcnt(8)" ::: "memory");
        } else {
            asm volatile("s_waitcnt vmcnt(0)" ::: "memory");
        }
        __builtin_amdgcn_s_barrier();
        asm volatile("" ::: "memory");

#pragma unroll
        for (int kk = 0; kk < 2; ++kk) {
            const int co = kk ? co1 : co0;
            bf16x8 af[4], bf[4];
#pragma unroll
            for (int i = 0; i < 4; ++i)
                af[i] = *reinterpret_cast<const bf16x8*>(&sA[c][(wm + i * 16 + llo) * 64 + co]);
#pragma unroll
            for (int j = 0; j < 4; ++j)
                bf[j] = *reinterpret_cast<const bf16x8*>(&sB[c][(wn + j * 16 + llo) * 64 + co]);
#pragma unroll
            for (int i = 0; i < 4; ++i)
#pragma unroll
                for (int j = 0; j < 4; ++j)
                    acc[i][j] = __builtin_amdgcn_mfma_f32_16x16x32_bf16(af[i], bf[j], acc[i][j], 0, 0, 0);
        }

        asm volatile("" ::: "memory");
        __builtin_amdgcn_s_barrier();
        c ^= 1;
    }

    // ---- fused epilogue ----
    const int rm = bm + wm;       // wave's first output row (64-aligned)
    const int b = rm >> 11;
    const int tb = rm & 2047;
    const int col0 = bn + wn;     // wave's first output col (64-aligned)

    if (col0 < 2560) {
        const bool isq = col0 < 2048;
        const float* scale = isq ? qs : ks;
        const float mult = isq ? QMULT : 1.0f;
        float scl[4];
#pragma unroll
        for (int j = 0; j < 4; ++j) scl[j] = scale[j * 16 + llo];
        short* outp;
        if (isq)
            outp = qb + (size_t)(b * Hc + (col0 >> 6)) * 2048 * 64;
        else
            outp = kb + (size_t)(b * KVc + ((col0 - 2048) >> 6)) * 2048 * 64;
        // per-lane RoPE revolution factors: i_rope = (j&1)*16 + llo
        const float ir0 = INV2PI * exp2f(-ROPE_C * (float)llo);
        const float ir1 = INV2PI * exp2f(-ROPE_C * (float)(16 + llo));
#pragma unroll
        for (int i = 0; i < 4; ++i)
#pragma unroll
            for (int r = 0; r < 4; ++r) {
                float ss = 0.f;
#pragma unroll
                for (int j = 0; j < 4; ++j) ss += acc[i][j][r] * acc[i][j][r];
                ss += __shfl_xor(ss, 1);
                ss += __shfl_xor(ss, 2);
                ss += __shfl_xor(ss, 4);
                ss += __shfl_xor(ss, 8);
                float rinv = 1.0f / sqrtf(ss * (1.0f / 64.0f) + EPSc);
                float vn[4];
#pragma unroll
                for (int j = 0; j < 4; ++j) vn[j] = acc[i][j][r] * rinv * scl[j];
                const int t = tb + i * 16 + lhi * 4 + r;
                float f0 = (float)t * ir0;
                f0 -= floorf(f0);
                float f1 = (float)t * ir1;
                f1 -= floorf(f1);
                float sn0 = __builtin_amdgcn_sinf(f0), cs0 = __builtin_amdgcn_cosf(f0);
                float sn1 = __builtin_amdgcn_sinf(f1), cs1 = __builtin_amdgcn_cosf(f1);
                size_t base = (size_t)t * 64 + llo;
                outp[base]      = f2b((vn[0] * cs0 - vn[2] * sn0) * mult);
                outp[base + 16] = f2b((vn[1] * cs1 - vn[3] * sn1) * mult);
                outp[base + 32] = f2b((vn[2] * cs0 + vn[0] * sn0) * mult);
                outp[base + 48] = f2b((vn[3] * cs1 + vn[1] * sn1) * mult);
            }
    } else {
        // V: write transposed tile directly: vt[b][kv][tile][d(64)][t(64)]
        const int kv = (col0 - 2560) >> 6;
        const int tile = tb >> 6;   // rm 64-aligned -> one tile per wave
        short* dst = vt + ((size_t)(b * 8 + kv) * 32 + tile) * 4096;
#pragma unroll
        for (int i = 0; i < 4; ++i)
#pragma unroll
            for (int j = 0; j < 4; ++j) {
                short4v p4 = {f2b(acc[i][j][0]), f2b(acc[i][j][1]),
                              f2b(acc[i][j][2]), f2b(acc[i][j][3])};
                *reinterpret_cast<short4v*>(
                    &dst[(j * 16 + llo) * 64 + i * 16 + lhi * 4]) = p4;
            }
    }
}

// ---------------------------------------------------------------------------
// GEMM: C(MxN) = A(MxK,bf16) * Bt(NxK,bf16)^T  (used for output projection)
// 128x128 tile, BK=64, dbuf + counted vmcnt + XOR chunk-swizzle.
// ---------------------------------------------------------------------------
template <typename CT>
__global__ __launch_bounds__(256) void gemm_bt(const short* __restrict__ A,
                                               const short* __restrict__ Bt,
                                               CT* __restrict__ C, int M, int N, int K) {
    __shared__ __align__(16) short sA[2][128 * 64];
    __shared__ __align__(16) short sB[2][128 * 64];

    const int tid = threadIdx.x;
    const int wave = tid >> 6, lane = tid & 63;
    const int lhi = lane >> 4, llo = lane & 15;
    int bx = blockIdx.x, by = blockIdx.y;
    xcd_swizzle(gridDim.x, bx, by);
    const int bm = by * 128, bn = bx * 128;
    const int wm = (wave >> 1) * 64, wn = (wave & 1) * 64;

    const short* apt[4];
    const short* bpt[4];
#pragma unroll
    for (int l = 0; l < 4; ++l) {
        int c = l * 256 + tid;
        int r = c >> 3, ck = (c & 7) ^ (r & 7);
        apt[l] = A + (size_t)(bm + r) * K + ck * 8;
        bpt[l] = Bt + (size_t)(bn + r) * K + ck * 8;
    }

    f32x4 acc[4][4] = {};

#pragma unroll
    for (int l = 0; l < 4; ++l) {
        GLOAD16(apt[l], &sA[0][(l * 256 + tid) * 8]);
        GLOAD16(bpt[l], &sB[0][(l * 256 + tid) * 8]);
    }
    int c = 0;
    const int co0 = ((lhi ^ (llo & 7)) << 3);
    const int co1 = (((4 + lhi) ^ (llo & 7)) << 3);

#pragma unroll 1
    for (int k0 = 0; k0 < K; k0 += 64) {
        if (k0 + 64 < K) {
            const int kn = k0 + 64;
#pragma unroll
            for (int l = 0; l < 4; ++l) {
                GLOAD16(apt[l] + kn, &sA[c ^ 1][(l * 256 + tid) * 8]);
                GLOAD16(bpt[l] + kn, &sB[c ^ 1][(l * 256 + tid) * 8]);
            }
            asm volatile("s_waitcnt vmcnt(8)" ::: "memory");
        } else {
            asm volatile("s_waitcnt vmcnt(0)" ::: "memory");
        }
        __builtin_amdgcn_s_barrier();
        asm volatile("" ::: "memory");

#pragma unroll
        for (int kk = 0; kk < 2; ++kk) {
            const int co = kk ? co1 : co0;
            bf16x8 af[4], bf[4];
#pragma unroll
            for (int i = 0; i < 4; ++i)
                af[i] = *reinterpret_cast<const bf16x8*>(&sA[c][(wm + i * 16 + llo) * 64 + co]);
#pragma unroll
            for (int j = 0; j < 4; ++j)
                bf[j] = *reinterpret_cast<const bf16x8*>(&sB[c][(wn + j * 16 + llo) * 64 + co]);
#pragma unroll
            for (int i = 0; i < 4; ++i)
#pragma unroll
                for (int j = 0; j < 4; ++j)
                    acc[i][j] = __builtin_amdgcn_mfma_f32_16x16x32_bf16(af[i], bf[j], acc[i][j], 0, 0, 0);
        }

        asm volatile("" ::: "memory");
        __builtin_amdgcn_s_barrier();
        c ^= 1;
    }

#pragma unroll
    for (int i = 0; i < 4; ++i)
#pragma unroll
        for (int j = 0; j < 4; ++j)
#pragma unroll
            for (int r = 0; r < 4; ++r) {
                size_t idx = (size_t)(bm + wm + i * 16 + lhi * 4 + r) * N + bn + wn + j * 16 + llo;
                if constexpr (sizeof(CT) == 2)
                    C[idx] = f2b(acc[i][j][r]);
                else
                    C[idx] = acc[i][j][r];
            }
}

// ---------------------------------------------------------------------------
// Flash attention, causal GQA, swapped-QK^T form, double-buffered K/V,
// load-balanced pairing, defer-max online softmax, setprio around MFMA.
// grid (8, 32, 2), 256 thr.
// ---------------------------------------------------------------------------
__global__ __launch_bounds__(256) void attn_fwd(const short* __restrict__ Qb,
                                                const short* __restrict__ Kb,
                                                const short* __restrict__ Vt,
                                                short* __restrict__ Ob) {
    __shared__ __align__(16) short sK[2][64 * 64];
    __shared__ __align__(16) short sV[2][64 * 64];
    __shared__ __align__(16) short sP[4][32 * 72];

    const int pair = blockIdx.x;
    const int h = blockIdx.y, b = blockIdx.z;
    const int kvh = h >> 2;
    const int tid = threadIdx.x, wave = tid >> 6, lane = tid & 63;
    const int lhi = lane >> 4, llo = lane & 15;

    const short* Qp = Qb + (size_t)(b * Hc + h) * Tc * 64;
    const short* Kp = Kb + (size_t)(b * KVc + kvh) * Tc * 64;
    const short* Vp = Vt + (size_t)(b * KVc + kvh) * 32 * 4096;

    const int srow0 = tid >> 3, sslot0 = tid & 7;
    const int srow1 = (256 + tid) >> 3, sslot1 = tid & 7;
    const int soff0 = (sslot0 ^ (srow0 & 7)) * 8;
    const int soff1 = (sslot1 ^ (srow1 & 7)) * 8;

#pragma unroll 1
    for (int sub = 0; sub < 2; ++sub) {
        const int qt = sub ? pair : 15 - pair;
        const int Q0 = qt * 128 + wave * 32;
        const int ktmax_w = (Q0 + 31) >> 6;
        const int nkt = 2 * qt + 2;

        bf16x8 qf[2][2];
#pragma unroll
        for (int q16 = 0; q16 < 2; ++q16)
#pragma unroll
            for (int kk = 0; kk < 2; ++kk)
                qf[q16][kk] = *reinterpret_cast<const bf16x8*>(
                    Qp + (size_t)(Q0 + q16 * 16 + llo) * 64 + kk * 32 + lhi * 8);

        f32x4 o[2][4] = {};
        float mreg[2] = {-1e30f, -1e30f};
        float lreg[2] = {0.f, 0.f};

        {
            GLOAD16(Kp + (size_t)srow0 * 64 + soff0, &sK[0][tid * 8]);
            GLOAD16(Vp + (size_t)srow0 * 64 + soff0, &sV[0][tid * 8]);
            GLOAD16(Kp + (size_t)srow1 * 64 + soff1, &sK[0][(256 + tid) * 8]);
            GLOAD16(Vp + (size_t)srow1 * 64 + soff1, &sV[0][(256 + tid) * 8]);
        }
        int c = 0;

#pragma unroll 1
        for (int kt = 0; kt < nkt; ++kt) {
            const bool has_next = (kt + 1) < nkt;
            if (has_next) {
                const size_t kbase = (size_t)(kt + 1) * 4096;
                GLOAD16(Kp + kbase + srow0 * 64 + soff0, &sK[c ^ 1][tid * 8]);
                GLOAD16(Vp + kbase + srow0 * 64 + soff0, &sV[c ^ 1][tid * 8]);
                GLOAD16(Kp + kbase + srow1 * 64 + soff1, &sK[c ^ 1][(256 + tid) * 8]);
                GLOAD16(Vp + kbase + srow1 * 64 + soff1, &sV[c ^ 1][(256 + tid) * 8]);
                asm volatile("s_waitcnt vmcnt(4)" ::: "memory");
            } else {
                asm volatile("s_waitcnt vmcnt(0)" ::: "memory");
            }
            __builtin_amdgcn_s_barrier();
            asm volatile("" ::: "memory");

            if (kt <= ktmax_w) {
                const short* sKc = sK[c];
                const short* sVc = sV[c];
                f32x4 st[2][4];
                __builtin_amdgcn_s_setprio(1);
#pragma unroll
                for (int n = 0; n < 4; ++n) {
                    int krow = n * 16 + llo;
                    bf16x8 ka0 = *reinterpret_cast<const bf16x8*>(
                        &sKc[krow * 64 + ((lhi ^ (krow & 7)) << 3)]);
                    bf16x8 ka1 = *reinterpret_cast<const bf16x8*>(
                        &sKc[krow * 64 + (((4 + lhi) ^ (krow & 7)) << 3)]);
                    f32x4 z = {0.f, 0.f, 0.f, 0.f};
                    st[0][n] = __builtin_amdgcn_mfma_f32_16x16x32_bf16(ka0, qf[0][0], z, 0, 0, 0);
                    st[0][n] = __builtin_amdgcn_mfma_f32_16x16x32_bf16(ka1, qf[0][1], st[0][n], 0, 0, 0);
                    st[1][n] = __builtin_amdgcn_mfma_f32_16x16x32_bf16(ka0, qf[1][0], z, 0, 0, 0);
                    st[1][n] = __builtin_amdgcn_mfma_f32_16x16x32_bf16(ka1, qf[1][1], st[1][n], 0, 0, 0);
                }
                __builtin_amdgcn_s_setprio(0);
                if (kt == ktmax_w) {
#pragma unroll
                    for (int q16 = 0; q16 < 2; ++q16) {
                        int qg = Q0 + q16 * 16 + llo;
#pragma unroll
                        for (int n = 0; n < 4; ++n)
#pragma unroll
                            for (int r = 0; r < 4; ++r) {
                                int kvg = kt * 64 + n * 16 + lhi * 4 + r;
                                if (kvg > qg) st[q16][n][r] = -1e30f;
                            }
                    }
                }
                float pm[2];
#pragma unroll
                for (int q16 = 0; q16 < 2; ++q16) {
                    // max3-friendly tree
                    float r0 = fmaxf(fmaxf(st[q16][0][0], st[q16][0][1]),
                                     fmaxf(st[q16][0][2], st[q16][0][3]));
                    float r1 = fmaxf(fmaxf(st[q16][1][0], st[q16][1][1]),
                                     fmaxf(st[q16][1][2], st[q16][1][3]));
                    float r2 = fmaxf(fmaxf(st[q16][2][0], st[q16][2][1]),
                                     fmaxf(st[q16][2][2], st[q16][2][3]));
                    float r3 = fmaxf(fmaxf(st[q16][3][0], st[q16][3][1]),
                                     fmaxf(st[q16][3][2], st[q16][3][3]));
                    float p = fmaxf(fmaxf(r0, r1), fmaxf(r2, r3));
                    p = fmaxf(p, __shfl_xor(p, 16));
                    p = fmaxf(p, __shfl_xor(p, 32));
                    pm[q16] = p;
                }
                bool defer = __all((pm[0] - mreg[0] <= 8.f) && (pm[1] - mreg[1] <= 8.f));
                if (!defer) {
                    float alpha[2];
#pragma unroll
                    for (int q16 = 0; q16 < 2; ++q16) {
                        float mn = fmaxf(mreg[q16], pm[q16]);
                        alpha[q16] = __builtin_amdgcn_exp2f(mreg[q16] - mn);
                        mreg[q16] = mn;
                        lreg[q16] *= alpha[q16];
                    }
#pragma unroll
                    for (int q16 = 0; q16 < 2; ++q16)
#pragma unroll
                        for (int r = 0; r < 4; ++r) {
                            float ar = __shfl(alpha[q16], lhi * 4 + r);
#pragma unroll
                            for (int j = 0; j < 4; ++j) o[q16][j][r] *= ar;
                        }
                }
#pragma unroll
                for (int q16 = 0; q16 < 2; ++q16) {
                    float ps = 0.f;
#pragma unroll
                    for (int n = 0; n < 4; ++n)
#pragma unroll
                        for (int r = 0; r < 4; ++r) {
                            float p = __builtin_amdgcn_exp2f(st[q16][n][r] - mreg[q16]);
                            st[q16][n][r] = p;
                            ps += p;
                        }
                    ps += __shfl_xor(ps, 16);
                    ps += __shfl_xor(ps, 32);
                    lreg[q16] += ps;
                }
#pragma unroll
                for (int q16 = 0; q16 < 2; ++q16)
#pragma unroll
                    for (int n = 0; n < 4; ++n) {
                        short4v p4 = {f2b(st[q16][n][0]), f2b(st[q16][n][1]),
                                      f2b(st[q16][n][2]), f2b(st[q16][n][3])};
                        *reinterpret_cast<short4v*>(
                            &sP[wave][(q16 * 16 + llo) * 72 + n * 16 + lhi * 4]) = p4;
                    }
                __builtin_amdgcn_s_setprio(1);
#pragma unroll
                for (int kk = 0; kk < 2; ++kk) {
                    bf16x8 pa0 = *reinterpret_cast<const bf16x8*>(
                        &sP[wave][(0 * 16 + llo) * 72 + kk * 32 + lhi * 8]);
                    bf16x8 pa1 = *reinterpret_cast<const bf16x8*>(
                        &sP[wave][(1 * 16 + llo) * 72 + kk * 32 + lhi * 8]);
#pragma unroll
                    for (int j = 0; j < 4; ++j) {
                        int vrow = j * 16 + llo;
                        bf16x8 vf = *reinterpret_cast<const bf16x8*>(
                            &sVc[vrow * 64 + ((((kk * 4) + lhi) ^ (vrow & 7)) << 3)]);
                        o[0][j] = __builtin_amdgcn_mfma_f32_16x16x32_bf16(pa0, vf, o[0][j], 0, 0, 0);
                        o[1][j] = __builtin_amdgcn_mfma_f32_16x16x32_bf16(pa1, vf, o[1][j], 0, 0, 0);
                    }
                }
                __builtin_amdgcn_s_setprio(0);
            }
            asm volatile("" ::: "memory");
            __builtin_amdgcn_s_barrier();
            c ^= 1;
        }

#pragma unroll
        for (int q16 = 0; q16 < 2; ++q16) {
            float inv = 1.0f / lreg[q16];
#pragma unroll
            for (int r = 0; r < 4; ++r) {
                float ivr = __shfl(inv, lhi * 4 + r);
                int qrow = Q0 + q16 * 16 + lhi * 4 + r;
#pragma unroll
                for (int j = 0; j < 4; ++j)
                    Ob[((size_t)(b * Tc + qrow)) * 2048 + h * 64 + j * 16 + llo] =
                        f2b(o[q16][j][r] * ivr);
            }
        }
    }
}

// ---------------------------------------------------------------------------
extern "C" void kernel_launch(void* const* d_in, const int* in_sizes, int n_in,
                              void* d_out, int out_size, void* d_ws, size_t ws_size,
                              hipStream_t stream) {
    const float* x  = (const float*)d_in[0];
    const float* Wq = (const float*)d_in[1];
    const float* Wk = (const float*)d_in[2];
    const float* Wv = (const float*)d_in[3];
    const float* Wo = (const float*)d_in[4];
    const float* qs = (const float*)d_in[5];
    const float* ks = (const float*)d_in[6];
    float* out = (float*)d_out;

    char* w = (char*)d_ws;
    short* xb    = (short*)(w);                 // 16,777,216  (later: ob)
    short* WqkvT = (short*)(w + 16777216);      // 12,582,912
    short* WoT   = (short*)(w + 29360128);      //  8,388,608
    short* vt    = (short*)(w + 37748736);      //  8,388,608  (B,KV,32,64,64)
    short* qb    = (short*)(w + 62914560);      // 16,777,216
    short* kb    = (short*)(w + 79691776);      //  4,194,304
    short* ob    = xb;                          // alias (xb dead after proj)

    dim3 blk(256);
    // prep: x convert + all weight transposes in one launch
    prep_all<<<dim3(32, 32, 5), blk, 0, stream>>>(x, Wq, Wk, Wv, Wo, xb, WqkvT, WoT);
    // fused QKV projection + RMSNorm/RoPE epilogue + V-transpose -> qb, kb, vt
    gemm_proj<<<dim3(24, 32), blk, 0, stream>>>(xb, WqkvT, qs, ks, qb, kb, vt);
    // flash attention
    attn_fwd<<<dim3(8, 32, 2), blk, 0, stream>>>(qb, kb, vt, ob);
    // output projection (f32 out)
    gemm_bt<float><<<dim3(16, 32), blk, 0, stream>>>(ob, WoT, out, 4096, 2048, 2048);
}

// Round 12
// 218.498 us; speedup vs baseline: 1.4578x; 1.0071x over previous
//
#include <hip/hip_runtime.h>
#include <hip/hip_bf16.h>

typedef __attribute__((ext_vector_type(4))) float f32x4;
typedef __attribute__((ext_vector_type(8))) short bf16x8;
typedef __attribute__((ext_vector_type(4))) short short4v;

#define DEVI __device__ __forceinline__

constexpr int Bc = 2, Tc = 2048, Dc = 2048, Hc = 32, KVc = 8, HDc = 64;
constexpr int GRP = Hc / KVc;  // 4
constexpr float EPSc = 1e-6f;
// SCALE * log2(e) folded into Q so softmax uses exp2
constexpr float QMULT = 0.125f * 1.4426950408889634f;
constexpr float INV2PI = 0.15915494309189535f;
constexpr float ROPE_C = 0.41524101186092029f;  // log2(10000)/32

DEVI short f2b(float f) {
    __hip_bfloat16 h = __float2bfloat16(f);
    short s;
    __builtin_memcpy(&s, &h, sizeof(short));
    return s;
}
DEVI float b2f(short s) {
    unsigned int u = ((unsigned int)(unsigned short)s) << 16;
    float f;
    __builtin_memcpy(&f, &u, sizeof(float));
    return f;
}

#define GLOAD16(g, l)                                                        \
    __builtin_amdgcn_global_load_lds(                                        \
        (const __attribute__((address_space(1))) void*)(g),                  \
        (__attribute__((address_space(3))) void*)(l), 16, 0, 0)

// ---------------------------------------------------------------------------
// prep: weight transposes f32 (2048 x C) -> bf16 (C x 2048) (z=0..3) and
// x f32 -> bf16 convert (z=4), one launch.  grid (32, 32, 5).
// ---------------------------------------------------------------------------
__global__ __launch_bounds__(256) void prep_all(const float* __restrict__ x,
                                                const float* __restrict__ Wq,
                                                const float* __restrict__ Wk,
                                                const float* __restrict__ Wv,
                                                const float* __restrict__ Wo,
                                                short* __restrict__ xb,
                                                short* __restrict__ WqkvT,
                                                short* __restrict__ WoT) {
    const int z = blockIdx.z;
    if (z == 4) {  // convert x: 8.4M elems, 1024 blocks, 4 passes of 8/thread
        size_t base = ((size_t)(blockIdx.y * 32 + blockIdx.x) * 256 + threadIdx.x) * 8;
#pragma unroll
        for (int p = 0; p < 4; ++p) {
            size_t i = base + (size_t)p * 2097152;
            float4 a = *reinterpret_cast<const float4*>(x + i);
            float4 b = *reinterpret_cast<const float4*>(x + i + 4);
            bf16x8 o = {f2b(a.x), f2b(a.y), f2b(a.z), f2b(a.w),
                        f2b(b.x), f2b(b.y), f2b(b.z), f2b(b.w)};
            *reinterpret_cast<bf16x8*>(xb + i) = o;
        }
        return;
    }
    const float* src;
    short* dst;
    int C;
    if (z == 0)      { src = Wq; dst = WqkvT;                          C = 2048; }
    else if (z == 1) { src = Wk; dst = WqkvT + (size_t)2048 * 2048;    C = 512; }
    else if (z == 2) { src = Wv; dst = WqkvT + (size_t)2560 * 2048;    C = 512; }
    else             { src = Wo; dst = WoT;                            C = 2048; }
    const int n0 = blockIdx.x * 64, k0 = blockIdx.y * 64;
    if (n0 >= C) return;

    __shared__ __align__(16) short t[64][72];
    const int rl = threadIdx.x >> 2, q = threadIdx.x & 3;
#pragma unroll
    for (int jj = 0; jj < 4; ++jj) {
        float4 v = *reinterpret_cast<const float4*>(src + (size_t)(k0 + rl) * C + n0 + q * 16 + jj * 4);
        short4v s = {f2b(v.x), f2b(v.y), f2b(v.z), f2b(v.w)};
        *reinterpret_cast<short4v*>(&t[rl][q * 16 + jj * 4]) = s;
    }
    __syncthreads();
    alignas(16) short buf[16];
#pragma unroll
    for (int e = 0; e < 16; ++e) buf[e] = t[q * 16 + e][rl];
    short* d = dst + (size_t)(n0 + rl) * 2048 + k0 + q * 16;
    *reinterpret_cast<int4*>(d) = reinterpret_cast<int4*>(buf)[0];
    *reinterpret_cast<int4*>(d + 8) = reinterpret_cast<int4*>(buf)[1];
}

// bijective XCD swizzle of flattened block id (nwg % 8 == 0)
DEVI void xcd_swizzle(int nx, int& bx, int& by) {
    int nwg = nx * gridDim.y;
    int fb = by * nx + bx;
    int cpx = nwg >> 3;
    int swz = (fb & 7) * cpx + (fb >> 3);
    by = swz / nx;
    bx = swz - by * nx;
}

// ---------------------------------------------------------------------------
// QKV-projection GEMM with fused RMSNorm+RoPE epilogue and fused V-transpose.
// C(4096x3072) = xb(4096x2048) * WqkvT(3072x2048)^T, 128x128 tile, BK=64,
// 256 thr (4 waves 2x2 of 64x64).  Each wave's 64 output cols = one head.
// Epilogue: cols<2048 -> RMSNorm(qs)+RoPE+QMULT -> qb (B,H,T,64)
//           cols 2048-2559 -> RMSNorm(ks)+RoPE -> kb (B,KV,T,64)
//           cols>=2560 -> transposed bf16 tiles vt[b][kv][tile][d64][t64]
// ---------------------------------------------------------------------------
__global__ __launch_bounds__(256) void gemm_proj(const short* __restrict__ A,
                                                 const short* __restrict__ Bt,
                                                 const float* __restrict__ qs,
                                                 const float* __restrict__ ks,
                                                 short* __restrict__ qb,
                                                 short* __restrict__ kb,
                                                 short* __restrict__ vt) {
    constexpr int K = 2048;
    __shared__ __align__(16) short sA[2][128 * 64];
    __shared__ __align__(16) short sB[2][128 * 64];

    const int tid = threadIdx.x;
    const int wave = tid >> 6, lane = tid & 63;
    const int lhi = lane >> 4, llo = lane & 15;
    int bx = blockIdx.x, by = blockIdx.y;
    xcd_swizzle(24, bx, by);
    const int bm = by * 128, bn = bx * 128;
    const int wm = (wave >> 1) * 64, wn = (wave & 1) * 64;

    const short* apt[4];
    const short* bpt[4];
#pragma unroll
    for (int l = 0; l < 4; ++l) {
        int c = l * 256 + tid;
        int r = c >> 3, ck = (c & 7) ^ (r & 7);
        apt[l] = A + (size_t)(bm + r) * K + ck * 8;
        bpt[l] = Bt + (size_t)(bn + r) * K + ck * 8;
    }

    f32x4 acc[4][4] = {};

#pragma unroll
    for (int l = 0; l < 4; ++l) {
        GLOAD16(apt[l], &sA[0][(l * 256 + tid) * 8]);
        GLOAD16(bpt[l], &sB[0][(l * 256 + tid) * 8]);
    }
    int c = 0;
    const int co0 = ((lhi ^ (llo & 7)) << 3);
    const int co1 = (((4 + lhi) ^ (llo & 7)) << 3);

#pragma unroll 1
    for (int k0 = 0; k0 < K; k0 += 64) {
        if (k0 + 64 < K) {
            const int kn = k0 + 64;
#pragma unroll
            for (int l = 0; l < 4; ++l) {
                GLOAD16(apt[l] + kn, &sA[c ^ 1][(l * 256 + tid) * 8]);
                GLOAD16(bpt[l] + kn, &sB[c ^ 1][(l * 256 + tid) * 8]);
            }
            asm volatile("s_waitcnt vmcnt(8)" ::: "memory");
        } else {
            asm volatile("s_waitcnt vmcnt(0)" ::: "memory");
        }
        __builtin_amdgcn_s_barrier();
        asm volatile("" ::: "memory");

#pragma unroll
        for (int kk = 0; kk < 2; ++kk) {
            const int co = kk ? co1 : co0;
            bf16x8 af[4], bf[4];
#pragma unroll
            for (int i = 0; i < 4; ++i)
                af[i] = *reinterpret_cast<const bf16x8*>(&sA[c][(wm + i * 16 + llo) * 64 + co]);
#pragma unroll
            for (int j = 0; j < 4; ++j)
                bf[j] = *reinterpret_cast<const bf16x8*>(&sB[c][(wn + j * 16 + llo) * 64 + co]);
#pragma unroll
            for (int i = 0; i < 4; ++i)
#pragma unroll
                for (int j = 0; j < 4; ++j)
                    acc[i][j] = __builtin_amdgcn_mfma_f32_16x16x32_bf16(af[i], bf[j], acc[i][j], 0, 0, 0);
        }

        asm volatile("" ::: "memory");
        __builtin_amdgcn_s_barrier();
        c ^= 1;
    }

    // ---- fused epilogue ----
    const int rm = bm + wm;       // wave's first output row (64-aligned)
    const int b = rm >> 11;
    const int tb = rm & 2047;
    const int col0 = bn + wn;     // wave's first output col (64-aligned)

    if (col0 < 2560) {
        const bool isq = col0 < 2048;
        const float* scale = isq ? qs : ks;
        const float mult = isq ? QMULT : 1.0f;
        float scl[4];
#pragma unroll
        for (int j = 0; j < 4; ++j) scl[j] = scale[j * 16 + llo];
        short* outp;
        if (isq)
            outp = qb + (size_t)(b * Hc + (col0 >> 6)) * 2048 * 64;
        else
            outp = kb + (size_t)(b * KVc + ((col0 - 2048) >> 6)) * 2048 * 64;
        // per-lane RoPE revolution factors: i_rope = (j&1)*16 + llo
        const float ir0 = INV2PI * exp2f(-ROPE_C * (float)llo);
        const float ir1 = INV2PI * exp2f(-ROPE_C * (float)(16 + llo));
#pragma unroll
        for (int i = 0; i < 4; ++i)
#pragma unroll
            for (int r = 0; r < 4; ++r) {
                float ss = 0.f;
#pragma unroll
                for (int j = 0; j < 4; ++j) ss += acc[i][j][r] * acc[i][j][r];
                ss += __shfl_xor(ss, 1);
                ss += __shfl_xor(ss, 2);
                ss += __shfl_xor(ss, 4);
                ss += __shfl_xor(ss, 8);
                float rinv = 1.0f / sqrtf(ss * (1.0f / 64.0f) + EPSc);
                float vn[4];
#pragma unroll
                for (int j = 0; j < 4; ++j) vn[j] = acc[i][j][r] * rinv * scl[j];
                const int t = tb + i * 16 + lhi * 4 + r;
                float f0 = (float)t * ir0;
                f0 -= floorf(f0);
                float f1 = (float)t * ir1;
                f1 -= floorf(f1);
                float sn0 = __builtin_amdgcn_sinf(f0), cs0 = __builtin_amdgcn_cosf(f0);
                float sn1 = __builtin_amdgcn_sinf(f1), cs1 = __builtin_amdgcn_cosf(f1);
                size_t base = (size_t)t * 64 + llo;
                outp[base]      = f2b((vn[0] * cs0 - vn[2] * sn0) * mult);
                outp[base + 16] = f2b((vn[1] * cs1 - vn[3] * sn1) * mult);
                outp[base + 32] = f2b((vn[2] * cs0 + vn[0] * sn0) * mult);
                outp[base + 48] = f2b((vn[3] * cs1 + vn[1] * sn1) * mult);
            }
    } else {
        // V: write transposed tile directly: vt[b][kv][tile][d(64)][t(64)]
        const int kv = (col0 - 2560) >> 6;
        const int tile = tb >> 6;   // rm 64-aligned -> one tile per wave
        short* dst = vt + ((size_t)(b * 8 + kv) * 32 + tile) * 4096;
#pragma unroll
        for (int i = 0; i < 4; ++i)
#pragma unroll
            for (int j = 0; j < 4; ++j) {
                short4v p4 = {f2b(acc[i][j][0]), f2b(acc[i][j][1]),
                              f2b(acc[i][j][2]), f2b(acc[i][j][3])};
                *reinterpret_cast<short4v*>(
                    &dst[(j * 16 + llo) * 64 + i * 16 + lhi * 4]) = p4;
            }
    }
}

// ---------------------------------------------------------------------------
// GEMM: C(MxN) = A(MxK,bf16) * Bt(NxK,bf16)^T  (used for output projection)
// 128x128 tile, BK=64, dbuf + counted vmcnt + XOR chunk-swizzle.
// ---------------------------------------------------------------------------
template <typename CT>
__global__ __launch_bounds__(256) void gemm_bt(const short* __restrict__ A,
                                               const short* __restrict__ Bt,
                                               CT* __restrict__ C, int M, int N, int K) {
    __shared__ __align__(16) short sA[2][128 * 64];
    __shared__ __align__(16) short sB[2][128 * 64];

    const int tid = threadIdx.x;
    const int wave = tid >> 6, lane = tid & 63;
    const int lhi = lane >> 4, llo = lane & 15;
    int bx = blockIdx.x, by = blockIdx.y;
    xcd_swizzle(gridDim.x, bx, by);
    const int bm = by * 128, bn = bx * 128;
    const int wm = (wave >> 1) * 64, wn = (wave & 1) * 64;

    const short* apt[4];
    const short* bpt[4];
#pragma unroll
    for (int l = 0; l < 4; ++l) {
        int c = l * 256 + tid;
        int r = c >> 3, ck = (c & 7) ^ (r & 7);
        apt[l] = A + (size_t)(bm + r) * K + ck * 8;
        bpt[l] = Bt + (size_t)(bn + r) * K + ck * 8;
    }

    f32x4 acc[4][4] = {};

#pragma unroll
    for (int l = 0; l < 4; ++l) {
        GLOAD16(apt[l], &sA[0][(l * 256 + tid) * 8]);
        GLOAD16(bpt[l], &sB[0][(l * 256 + tid) * 8]);
    }
    int c = 0;
    const int co0 = ((lhi ^ (llo & 7)) << 3);
    const int co1 = (((4 + lhi) ^ (llo & 7)) << 3);

#pragma unroll 1
    for (int k0 = 0; k0 < K; k0 += 64) {
        if (k0 + 64 < K) {
            const int kn = k0 + 64;
#pragma unroll
            for (int l = 0; l < 4; ++l) {
                GLOAD16(apt[l] + kn, &sA[c ^ 1][(l * 256 + tid) * 8]);
                GLOAD16(bpt[l] + kn, &sB[c ^ 1][(l * 256 + tid) * 8]);
            }
            asm volatile("s_waitcnt vmcnt(8)" ::: "memory");
        } else {
            asm volatile("s_waitcnt vmcnt(0)" ::: "memory");
        }
        __builtin_amdgcn_s_barrier();
        asm volatile("" ::: "memory");

#pragma unroll
        for (int kk = 0; kk < 2; ++kk) {
            const int co = kk ? co1 : co0;
            bf16x8 af[4], bf[4];
#pragma unroll
            for (int i = 0; i < 4; ++i)
                af[i] = *reinterpret_cast<const bf16x8*>(&sA[c][(wm + i * 16 + llo) * 64 + co]);
#pragma unroll
            for (int j = 0; j < 4; ++j)
                bf[j] = *reinterpret_cast<const bf16x8*>(&sB[c][(wn + j * 16 + llo) * 64 + co]);
#pragma unroll
            for (int i = 0; i < 4; ++i)
#pragma unroll
                for (int j = 0; j < 4; ++j)
                    acc[i][j] = __builtin_amdgcn_mfma_f32_16x16x32_bf16(af[i], bf[j], acc[i][j], 0, 0, 0);
        }

        asm volatile("" ::: "memory");
        __builtin_amdgcn_s_barrier();
        c ^= 1;
    }

#pragma unroll
    for (int i = 0; i < 4; ++i)
#pragma unroll
        for (int j = 0; j < 4; ++j)
#pragma unroll
            for (int r = 0; r < 4; ++r) {
                size_t idx = (size_t)(bm + wm + i * 16 + lhi * 4 + r) * N + bn + wn + j * 16 + llo;
                if constexpr (sizeof(CT) == 2)
                    C[idx] = f2b(acc[i][j][r]);
                else
                    C[idx] = acc[i][j][r];
            }
}

// ---------------------------------------------------------------------------
// Flash attention, causal GQA, swapped-QK^T form, double-buffered K/V,
// defer-max online softmax.  grid (64 hb, 16 qt-rank): one q-tile of 128 rows
// per block, longest tiles dispatched first (LPT); ~3 blocks/CU resident.
// 256 thr = 4 waves, 32 q rows per wave.
// ---------------------------------------------------------------------------
__global__ __launch_bounds__(256) void attn_fwd(const short* __restrict__ Qb,
                                                const short* __restrict__ Kb,
                                                const short* __restrict__ Vt,
                                                short* __restrict__ Ob) {
    __shared__ __align__(16) short sK[2][64 * 64];
    __shared__ __align__(16) short sV[2][64 * 64];
    __shared__ __align__(16) short sP[4][32 * 72];

    const int hb = blockIdx.x;           // 0..63: h*? -> h = hb & 31, b = hb >> 5
    const int qt = 15 - (int)blockIdx.y; // y=0 -> longest (qt=15) first
    const int h = hb & 31, b = hb >> 5;
    const int kvh = h >> 2;
    const int tid = threadIdx.x, wave = tid >> 6, lane = tid & 63;
    const int lhi = lane >> 4, llo = lane & 15;

    const short* Qp = Qb + (size_t)(b * Hc + h) * Tc * 64;
    const short* Kp = Kb + (size_t)(b * KVc + kvh) * Tc * 64;
    const short* Vp = Vt + (size_t)(b * KVc + kvh) * 32 * 4096;

    const int srow0 = tid >> 3, sslot0 = tid & 7;
    const int srow1 = (256 + tid) >> 3, sslot1 = tid & 7;
    const int soff0 = (sslot0 ^ (srow0 & 7)) * 8;
    const int soff1 = (sslot1 ^ (srow1 & 7)) * 8;

    const int Q0 = qt * 128 + wave * 32;
    const int ktmax_w = (Q0 + 31) >> 6;
    const int nkt = 2 * qt + 2;

    bf16x8 qf[2][2];
#pragma unroll
    for (int q16 = 0; q16 < 2; ++q16)
#pragma unroll
        for (int kk = 0; kk < 2; ++kk)
            qf[q16][kk] = *reinterpret_cast<const bf16x8*>(
                Qp + (size_t)(Q0 + q16 * 16 + llo) * 64 + kk * 32 + lhi * 8);

    f32x4 o[2][4] = {};
    float mreg[2] = {-1e30f, -1e30f};
    float lreg[2] = {0.f, 0.f};

    {
        GLOAD16(Kp + (size_t)srow0 * 64 + soff0, &sK[0][tid * 8]);
        GLOAD16(Vp + (size_t)srow0 * 64 + soff0, &sV[0][tid * 8]);
        GLOAD16(Kp + (size_t)srow1 * 64 + soff1, &sK[0][(256 + tid) * 8]);
        GLOAD16(Vp + (size_t)srow1 * 64 + soff1, &sV[0][(256 + tid) * 8]);
    }
    int c = 0;

#pragma unroll 1
    for (int kt = 0; kt < nkt; ++kt) {
        const bool has_next = (kt + 1) < nkt;
        if (has_next) {
            const size_t kbase = (size_t)(kt + 1) * 4096;
            GLOAD16(Kp + kbase + srow0 * 64 + soff0, &sK[c ^ 1][tid * 8]);
            GLOAD16(Vp + kbase + srow0 * 64 + soff0, &sV[c ^ 1][tid * 8]);
            GLOAD16(Kp + kbase + srow1 * 64 + soff1, &sK[c ^ 1][(256 + tid) * 8]);
            GLOAD16(Vp + kbase + srow1 * 64 + soff1, &sV[c ^ 1][(256 + tid) * 8]);
            asm volatile("s_waitcnt vmcnt(4)" ::: "memory");
        } else {
            asm volatile("s_waitcnt vmcnt(0)" ::: "memory");
        }
        __builtin_amdgcn_s_barrier();
        asm volatile("" ::: "memory");

        if (kt <= ktmax_w) {
            const short* sKc = sK[c];
            const short* sVc = sV[c];
            f32x4 st[2][4];
            __builtin_amdgcn_s_setprio(1);
#pragma unroll
            for (int n = 0; n < 4; ++n) {
                int krow = n * 16 + llo;
                bf16x8 ka0 = *reinterpret_cast<const bf16x8*>(
                    &sKc[krow * 64 + ((lhi ^ (krow & 7)) << 3)]);
                bf16x8 ka1 = *reinterpret_cast<const bf16x8*>(
                    &sKc[krow * 64 + (((4 + lhi) ^ (krow & 7)) << 3)]);
                f32x4 z = {0.f, 0.f, 0.f, 0.f};
                st[0][n] = __builtin_amdgcn_mfma_f32_16x16x32_bf16(ka0, qf[0][0], z, 0, 0, 0);
                st[0][n] = __builtin_amdgcn_mfma_f32_16x16x32_bf16(ka1, qf[0][1], st[0][n], 0, 0, 0);
                st[1][n] = __builtin_amdgcn_mfma_f32_16x16x32_bf16(ka0, qf[1][0], z, 0, 0, 0);
                st[1][n] = __builtin_amdgcn_mfma_f32_16x16x32_bf16(ka1, qf[1][1], st[1][n], 0, 0, 0);
            }
            __builtin_amdgcn_s_setprio(0);
            if (kt == ktmax_w) {
#pragma unroll
                for (int q16 = 0; q16 < 2; ++q16) {
                    int qg = Q0 + q16 * 16 + llo;
#pragma unroll
                    for (int n = 0; n < 4; ++n)
#pragma unroll
                        for (int r = 0; r < 4; ++r) {
                            int kvg = kt * 64 + n * 16 + lhi * 4 + r;
                            if (kvg > qg) st[q16][n][r] = -1e30f;
                        }
                }
            }
            float pm[2];
#pragma unroll
            for (int q16 = 0; q16 < 2; ++q16) {
                float r0 = fmaxf(fmaxf(st[q16][0][0], st[q16][0][1]),
                                 fmaxf(st[q16][0][2], st[q16][0][3]));
                float r1 = fmaxf(fmaxf(st[q16][1][0], st[q16][1][1]),
                                 fmaxf(st[q16][1][2], st[q16][1][3]));
                float r2 = fmaxf(fmaxf(st[q16][2][0], st[q16][2][1]),
                                 fmaxf(st[q16][2][2], st[q16][2][3]));
                float r3 = fmaxf(fmaxf(st[q16][3][0], st[q16][3][1]),
                                 fmaxf(st[q16][3][2], st[q16][3][3]));
                float p = fmaxf(fmaxf(r0, r1), fmaxf(r2, r3));
                p = fmaxf(p, __shfl_xor(p, 16));
                p = fmaxf(p, __shfl_xor(p, 32));
                pm[q16] = p;
            }
            bool defer = __all((pm[0] - mreg[0] <= 8.f) && (pm[1] - mreg[1] <= 8.f));
            if (!defer) {
                float alpha[2];
#pragma unroll
                for (int q16 = 0; q16 < 2; ++q16) {
                    float mn = fmaxf(mreg[q16], pm[q16]);
                    alpha[q16] = __builtin_amdgcn_exp2f(mreg[q16] - mn);
                    mreg[q16] = mn;
                    lreg[q16] *= alpha[q16];
                }
#pragma unroll
                for (int q16 = 0; q16 < 2; ++q16)
#pragma unroll
                    for (int r = 0; r < 4; ++r) {
                        float ar = __shfl(alpha[q16], lhi * 4 + r);
#pragma unroll
                        for (int j = 0; j < 4; ++j) o[q16][j][r] *= ar;
                    }
            }
#pragma unroll
            for (int q16 = 0; q16 < 2; ++q16) {
                float ps = 0.f;
#pragma unroll
                for (int n = 0; n < 4; ++n)
#pragma unroll
                    for (int r = 0; r < 4; ++r) {
                        float p = __builtin_amdgcn_exp2f(st[q16][n][r] - mreg[q16]);
                        st[q16][n][r] = p;
                        ps += p;
                    }
                ps += __shfl_xor(ps, 16);
                ps += __shfl_xor(ps, 32);
                lreg[q16] += ps;
            }
#pragma unroll
            for (int q16 = 0; q16 < 2; ++q16)
#pragma unroll
                for (int n = 0; n < 4; ++n) {
                    short4v p4 = {f2b(st[q16][n][0]), f2b(st[q16][n][1]),
                                  f2b(st[q16][n][2]), f2b(st[q16][n][3])};
                    *reinterpret_cast<short4v*>(
                        &sP[wave][(q16 * 16 + llo) * 72 + n * 16 + lhi * 4]) = p4;
                }
            __builtin_amdgcn_s_setprio(1);
#pragma unroll
            for (int kk = 0; kk < 2; ++kk) {
                bf16x8 pa0 = *reinterpret_cast<const bf16x8*>(
                    &sP[wave][(0 * 16 + llo) * 72 + kk * 32 + lhi * 8]);
                bf16x8 pa1 = *reinterpret_cast<const bf16x8*>(
                    &sP[wave][(1 * 16 + llo) * 72 + kk * 32 + lhi * 8]);
#pragma unroll
                for (int j = 0; j < 4; ++j) {
                    int vrow = j * 16 + llo;
                    bf16x8 vf = *reinterpret_cast<const bf16x8*>(
                        &sVc[vrow * 64 + ((((kk * 4) + lhi) ^ (vrow & 7)) << 3)]);
                    o[0][j] = __builtin_amdgcn_mfma_f32_16x16x32_bf16(pa0, vf, o[0][j], 0, 0, 0);
                    o[1][j] = __builtin_amdgcn_mfma_f32_16x16x32_bf16(pa1, vf, o[1][j], 0, 0, 0);
                }
            }
            __builtin_amdgcn_s_setprio(0);
        }
        asm volatile("" ::: "memory");
        __builtin_amdgcn_s_barrier();
        c ^= 1;
    }

#pragma unroll
    for (int q16 = 0; q16 < 2; ++q16) {
        float inv = 1.0f / lreg[q16];
#pragma unroll
        for (int r = 0; r < 4; ++r) {
            float ivr = __shfl(inv, lhi * 4 + r);
            int qrow = Q0 + q16 * 16 + lhi * 4 + r;
#pragma unroll
            for (int j = 0; j < 4; ++j)
                Ob[((size_t)(b * Tc + qrow)) * 2048 + h * 64 + j * 16 + llo] =
                    f2b(o[q16][j][r] * ivr);
        }
    }
}

// ---------------------------------------------------------------------------
extern "C" void kernel_launch(void* const* d_in, const int* in_sizes, int n_in,
                              void* d_out, int out_size, void* d_ws, size_t ws_size,
                              hipStream_t stream) {
    const float* x  = (const float*)d_in[0];
    const float* Wq = (const float*)d_in[1];
    const float* Wk = (const float*)d_in[2];
    const float* Wv = (const float*)d_in[3];
    const float* Wo = (const float*)d_in[4];
    const float* qs = (const float*)d_in[5];
    const float* ks = (const float*)d_in[6];
    float* out = (float*)d_out;

    char* w = (char*)d_ws;
    short* xb    = (short*)(w);                 // 16,777,216  (later: ob)
    short* WqkvT = (short*)(w + 16777216);      // 12,582,912
    short* WoT   = (short*)(w + 29360128);      //  8,388,608
    short* vt    = (short*)(w + 37748736);      //  8,388,608  (B,KV,32,64,64)
    short* qb    = (short*)(w + 62914560);      // 16,777,216
    short* kb    = (short*)(w + 79691776);      //  4,194,304
    short* ob    = xb;                          // alias (xb dead after proj)

    dim3 blk(256);
    // prep: x convert + all weight transposes in one launch
    prep_all<<<dim3(32, 32, 5), blk, 0, stream>>>(x, Wq, Wk, Wv, Wo, xb, WqkvT, WoT);
    // fused QKV projection + RMSNorm/RoPE epilogue + V-transpose -> qb, kb, vt
    gemm_proj<<<dim3(24, 32), blk, 0, stream>>>(xb, WqkvT, qs, ks, qb, kb, vt);
    // flash attention: 1024 blocks, longest q-tiles dispatched first (LPT)
    attn_fwd<<<dim3(64, 16), blk, 0, stream>>>(qb, kb, vt, ob);
    // output projection (f32 out)
    gemm_bt<float><<<dim3(16, 32), blk, 0, stream>>>(ob, WoT, out, 4096, 2048, 2048);
}